// Round 11
// baseline (147.102 us; speedup 1.0000x reference)
//
#include <hip/hip_runtime.h>
#include <hip/hip_bf16.h>
#include <stdint.h>
#include <math.h>

// CausalMultiheadRoPEAttn: B=2, S=2048, D=1024, H=16, Dh=64
// prep (bf16 casts + rope table) -> fused QKV gemm (+bias+rope, V transposed,
// padded stride; counted-vmcnt depth-2 pipelined K-loop, raw barriers)
// -> flash attention: swapped-operand 32x32x16 MFMA, in-register softmax,
//    KV-SPLIT strips (every wave <=16 iters, 1024 blocks, TLP via 3+ waves/
//    SIMD, single-buffered K/V frags, end-of-kernel LDS merge)
// -> out gemm (pipelined K-loop).

typedef __bf16 bf16;
typedef __attribute__((ext_vector_type(4))) __bf16 bf16x4;
typedef __attribute__((ext_vector_type(8))) __bf16 bf16x8;
typedef __attribute__((ext_vector_type(4))) float f32x4;
typedef __attribute__((ext_vector_type(16))) float f32x16;
typedef __attribute__((ext_vector_type(4))) uint32_t u32x4;

#define SEQN 2048
#define DMOD 1024
#define NHEAD 16
#define DHEAD 64
#define MTOT 4096
#define VSTR 2080   // padded Vt row stride (elements)
// 0.125 * log2(e): scores land in log2 domain -> softmax uses exp2
#define QSCALE_LOG2E 0.18033688011112042f

__device__ __forceinline__ void gload_lds16(const bf16* g, bf16* l) {
  __builtin_amdgcn_global_load_lds(
      (const __attribute__((address_space(1))) uint32_t*)g,
      (__attribute__((address_space(3))) uint32_t*)l,
      16, 0, 0);
}

__device__ __forceinline__ uint32_t cvtpk(float lo, float hi) {
  uint32_t r;
  asm("v_cvt_pk_bf16_f32 %0, %1, %2" : "=v"(r) : "v"(lo), "v"(hi));
  return r;
}

// ---------------------------------------------------------------- prep
__global__ __launch_bounds__(256) void prep_kernel(
    const float* __restrict__ X,
    const float* __restrict__ Wq, const float* __restrict__ Wk,
    const float* __restrict__ Wv, const float* __restrict__ Wo,
    bf16* __restrict__ Xb, bf16* __restrict__ Wqb, bf16* __restrict__ Wkb,
    bf16* __restrict__ Wvb, bf16* __restrict__ Wob,
    float* __restrict__ ctab, float* __restrict__ stab)
{
  const int tid = blockIdx.x * blockDim.x + threadIdx.x;
  const int nth = gridDim.x * blockDim.x;

  const float4* X4 = (const float4*)X;
  for (int i = tid; i < MTOT * DMOD / 4; i += nth) {
    float4 v = X4[i];
    bf16x4 o = { (bf16)v.x, (bf16)v.y, (bf16)v.z, (bf16)v.w };
    *(bf16x4*)(Xb + (size_t)i * 4) = o;
  }
  const float4* q4 = (const float4*)Wq;
  const float4* k4 = (const float4*)Wk;
  const float4* v4 = (const float4*)Wv;
  const float4* o4 = (const float4*)Wo;
  for (int i = tid; i < DMOD * DMOD / 4; i += nth) {
    float4 a = q4[i];
    float4 b = k4[i];
    float4 c = v4[i];
    float4 d = o4[i];
    *(bf16x4*)(Wqb + (size_t)i * 4) = bf16x4{ (bf16)a.x, (bf16)a.y, (bf16)a.z, (bf16)a.w };
    *(bf16x4*)(Wkb + (size_t)i * 4) = bf16x4{ (bf16)b.x, (bf16)b.y, (bf16)b.z, (bf16)b.w };
    *(bf16x4*)(Wvb + (size_t)i * 4) = bf16x4{ (bf16)c.x, (bf16)c.y, (bf16)c.z, (bf16)c.w };
    *(bf16x4*)(Wob + (size_t)i * 4) = bf16x4{ (bf16)d.x, (bf16)d.y, (bf16)d.z, (bf16)d.w };
  }
  for (int i = tid; i < SEQN * 32; i += nth) {
    const int s = i >> 5, p = i & 31;
    const float invf = (float)pow(10000.0, -(double)p / 32.0);
    const float ang = (float)s * invf;
    float sv, cv;
    sincosf(ang, &sv, &cv);
    ctab[i] = cv;
    stab[i] = sv;
  }
}

// ---------------------------------------------------------------- QKV gemm
// 128x128 tile, BK=32, 3-buffer LDS pipeline with counted vmcnt: tile s+2's
// global_load_lds stay in flight across the barriers; raw s_barrier.
__global__ __launch_bounds__(256) void gemm_qkv(
    const bf16* __restrict__ Xb,
    const bf16* __restrict__ Wqb, const bf16* __restrict__ Wkb, const bf16* __restrict__ Wvb,
    const float* __restrict__ bq, const float* __restrict__ bk, const float* __restrict__ bv,
    const float* __restrict__ ctab, const float* __restrict__ stab,
    bf16* __restrict__ Qb, bf16* __restrict__ Kb, bf16* __restrict__ Vtb)
{
  __shared__ bf16 sA[3][128 * 32];
  __shared__ bf16 sB[3][128 * 32];

  const int z = blockIdx.z;
  const bf16* Bm = (z == 0) ? Wqb : (z == 1) ? Wkb : Wvb;
  const float* bias = (z == 0) ? bq : (z == 1) ? bk : bv;

  const int t = threadIdx.x;
  const int lane = t & 63, l15 = lane & 15, g = lane >> 4;
  const int wave = t >> 6, wm = wave >> 1, wn = wave & 1;
  const int tileM = blockIdx.y * 128, tileN = blockIdx.x * 128;

  f32x4 acc[4][4] = {};

  const bf16* gA = Xb + (size_t)(tileM + (t >> 2)) * DMOD + (t & 3) * 8;
  const bf16* gB = Bm + (size_t)(tileN + (t >> 2)) * DMOD + (t & 3) * 8;

  auto stage = [&](int buf, int k0) {
    gload_lds16(gA + k0, &sA[buf][t * 8]);
    gload_lds16(gA + k0 + 64 * DMOD, &sA[buf][2048 + t * 8]);
    gload_lds16(gB + k0, &sB[buf][t * 8]);
    gload_lds16(gB + k0 + 64 * DMOD, &sB[buf][2048 + t * 8]);
  };

  stage(0, 0);
  stage(1, 32);

  const int NS = DMOD / 32;   // 32 K-steps
  int cur = 0;
  for (int s = 0; s < NS; ++s) {
    if (s + 2 < NS) {
      int pf = cur + 2; if (pf >= 3) pf -= 3;
      stage(pf, (s + 2) * 32);
      asm volatile("s_waitcnt vmcnt(8)" ::: "memory");   // tile s landed
    } else if (s + 1 < NS) {
      asm volatile("s_waitcnt vmcnt(4)" ::: "memory");
    } else {
      asm volatile("s_waitcnt vmcnt(0)" ::: "memory");
    }
    __builtin_amdgcn_s_barrier();
    asm volatile("" ::: "memory");

    const bf16* cA = sA[cur];
    const bf16* cB = sB[cur];
    bf16x8 af[4], bfr[4];
#pragma unroll
    for (int i = 0; i < 4; ++i)
      af[i] = *(const bf16x8*)(cA + (wm * 64 + i * 16 + l15) * 32 + g * 8);
#pragma unroll
    for (int j = 0; j < 4; ++j)
      bfr[j] = *(const bf16x8*)(cB + (wn * 64 + j * 16 + l15) * 32 + g * 8);
#pragma unroll
    for (int i = 0; i < 4; ++i)
#pragma unroll
      for (int j = 0; j < 4; ++j)
        acc[i][j] = __builtin_amdgcn_mfma_f32_16x16x32_bf16(af[i], bfr[j], acc[i][j], 0, 0, 0);

    asm volatile("" ::: "memory");
    __builtin_amdgcn_s_barrier();   // buf `cur` free for reuse
    cur = (cur == 2) ? 0 : cur + 1;
  }

#pragma unroll
  for (int j = 0; j < 4; ++j) {
    const int col = tileN + wn * 64 + j * 16 + l15;
    const float bcol = bias[col];
    const int h = col >> 6, d = col & 63;
#pragma unroll
    for (int i = 0; i < 4; ++i) {
#pragma unroll
      for (int r = 0; r < 4; ++r) {
        const int row = tileM + wm * 64 + i * 16 + g * 4 + r;
        const int b = row >> 11, s = row & (SEQN - 1);
        const float v = acc[i][j][r] + bcol;
        if (z != 2) {
          const int pair = d >> 1;
          const float cv = ctab[s * 32 + pair];
          const float sv = stab[s * 32 + pair];
          const float partner = __shfl_xor(v, 1);
          float rv = (d & 1) ? (partner * sv + v * cv) : (v * cv - partner * sv);
          if (z == 0) rv *= QSCALE_LOG2E;   // fold softmax scale+log2e into Q
          bf16* dst = (z == 0) ? Qb : Kb;
          dst[(((size_t)(b * NHEAD + h)) * SEQN + s) * DHEAD + d] = (bf16)rv;
        } else {
          Vtb[(((size_t)(b * NHEAD + h)) * DHEAD + d) * VSTR + s] = (bf16)v;
        }
      }
    }
  }
}

// ---------------------------------------------------------------- attention
// 1024 blocks (32 strip-pairs x 32 bh; bid&31=bh -> XCD-local heads), 4 waves.
// Each 32-row strip is processed by TWO waves splitting its KV range in half
// (every wave <= 16 iters). Single-buffered K/V fragments: latency hiding
// comes from 3+ waves/SIMD TLP (no forced launch bound -> no spill).
// Swapped-operand 32x32x16 MFMA, in-register softmax, P via cvt_pk +
// shfl_xor(32). End-of-kernel LDS merge (half1 -> LDS, half0 merges+stores).
__global__ __launch_bounds__(256) void attn_kernel(
    const bf16* __restrict__ Qb, const bf16* __restrict__ Kb,
    const bf16* __restrict__ Vt, bf16* __restrict__ AO)
{
  __shared__ float sMrg[2][64][35];   // [strip_in_block][lane][a0(16),a1(16),m,l]

  const int t = threadIdx.x;
  const int lane = t & 63, l31 = lane & 31, hi = lane >> 5;
  const int wave = t >> 6;
  const int sb = wave >> 1;       // strip in block (0/1)
  const int half = wave & 1;      // 0: low KV half, 1: high KV half

  const int bid = blockIdx.x;
  const int bh = bid & 31;                 // bid%8 == bh%8
  const int jq = 31 - (bid >> 5);          // heavy strips first
  const int qbase = (2 * jq + sb) * 32;
  const int qg = qbase + l31;              // this lane's q-row
  const int n = jq + 1;                    // KV-64 tiles covering the strip
  const int nA = (n + 1) >> 1;
  const int kv_lo = half ? nA : 0;
  const int kv_hi = half ? n : nA;

  const bf16* Kp = Kb + (size_t)bh * SEQN * DHEAD;
  const bf16* Vp = Vt + (size_t)bh * DHEAD * VSTR;
  const bf16* Qp = Qb + (size_t)bh * SEQN * DHEAD;
  const int b = bh >> 4, h = bh & 15;

  auto loadkv = [&](bf16x8 (&K)[2][4], bf16x8 (&V)[2][4], int kv0) {
#pragma unroll
    for (int s = 0; s < 2; ++s)
#pragma unroll
      for (int ch = 0; ch < 4; ++ch)
        K[s][ch] = *(const bf16x8*)(Kp + (size_t)(kv0 + 32 * s + l31) * DHEAD + 16 * ch + 8 * hi);
#pragma unroll
    for (int dblk = 0; dblk < 2; ++dblk)
#pragma unroll
      for (int c = 0; c < 4; ++c)
        V[dblk][c] = *(const bf16x8*)(Vp + (size_t)(dblk * 32 + l31) * VSTR + kv0 + 16 * c + 8 * hi);
  };

  bf16x8 qf[4];   // Q B-frag: col=q=l31, k=8hi+e (d=16ch+8hi+e)
#pragma unroll
  for (int ch = 0; ch < 4; ++ch)
    qf[ch] = *(const bf16x8*)(Qp + (size_t)qg * DHEAD + 16 * ch + 8 * hi);

  f32x16 a0 = {}, a1 = {};
  float m = -1e30f, l = 0.f;

  auto compute = [&](const bf16x8 (&K)[2][4], const bf16x8 (&V)[2][4], int kv0) {
    f32x16 s0 = {}, s1 = {};
#pragma unroll
    for (int ch = 0; ch < 4; ++ch) {
      s0 = __builtin_amdgcn_mfma_f32_32x32x16_bf16(K[0][ch], qf[ch], s0, 0, 0, 0);
      s1 = __builtin_amdgcn_mfma_f32_32x32x16_bf16(K[1][ch], qf[ch], s1, 0, 0, 0);
    }
    // tv[i]: score for key offset 32*(i>>4) + (i&3) + 8*((i>>2)&3) + 4*hi
    float tv[32];
#pragma unroll
    for (int i = 0; i < 16; ++i) { tv[i] = s0[i]; tv[16 + i] = s1[i]; }

    if (kv0 + 63 > qbase) {   // diagonal tile(s): causal mask (key > q)
#pragma unroll
      for (int i = 0; i < 32; ++i) {
        const int key = kv0 + 32 * (i >> 4) + ((i & 3) + 8 * ((i >> 2) & 3) + 4 * hi);
        if (key > qg) tv[i] = -1e30f;
      }
    }

    // row max: in-lane tree, then combine with partner half via shfl_xor(32)
    float red[16];
#pragma unroll
    for (int i = 0; i < 16; ++i) red[i] = fmaxf(tv[i], tv[i + 16]);
#pragma unroll
    for (int st = 8; st >= 1; st >>= 1)
#pragma unroll
      for (int i = 0; i < st; ++i) red[i] = fmaxf(red[i], red[i + st]);
    const float tmax = fmaxf(red[0], __shfl_xor(red[0], 32));
    const float mnew = fmaxf(m, tmax);
    const float alpha = __builtin_amdgcn_exp2f(m - mnew);
    m = mnew;

    // p = exp2(s - m), row sum (tree + shfl_xor(32))
#pragma unroll
    for (int i = 0; i < 32; ++i) tv[i] = __builtin_amdgcn_exp2f(tv[i] - mnew);
#pragma unroll
    for (int i = 0; i < 16; ++i) red[i] = tv[i] + tv[i + 16];
#pragma unroll
    for (int st = 8; st >= 1; st >>= 1)
#pragma unroll
      for (int i = 0; i < st; ++i) red[i] += red[i + st];
    l = l * alpha + (red[0] + __shfl_xor(red[0], 32));

#pragma unroll
    for (int i = 0; i < 16; ++i) { a0[i] *= alpha; a1[i] *= alpha; }

    // P B-frag, chunk c: lane (q,hi) needs keys 16c+8hi+e, e=0..7.
#pragma unroll
    for (int c = 0; c < 4; ++c) {
      const int b0 = (c & 1) * 8 + (c >> 1) * 16;   // base(2c); base(2c+1)=b0+4
      const uint32_t P0  = cvtpk(tv[b0 + 0], tv[b0 + 1]);
      const uint32_t P0b = cvtpk(tv[b0 + 2], tv[b0 + 3]);
      const uint32_t P1  = cvtpk(tv[b0 + 4], tv[b0 + 5]);
      const uint32_t P1b = cvtpk(tv[b0 + 6], tv[b0 + 7]);
      const uint32_t sP0  = (uint32_t)__shfl_xor((int)P0, 32);
      const uint32_t sP0b = (uint32_t)__shfl_xor((int)P0b, 32);
      const uint32_t sP1  = (uint32_t)__shfl_xor((int)P1, 32);
      const uint32_t sP1b = (uint32_t)__shfl_xor((int)P1b, 32);
      u32x4 pw;
      pw[0] = hi ? sP1  : P0;
      pw[1] = hi ? sP1b : P0b;
      pw[2] = hi ? P1   : sP0;
      pw[3] = hi ? P1b  : sP0b;
      const bf16x8 pf = __builtin_bit_cast(bf16x8, pw);
      a0 = __builtin_amdgcn_mfma_f32_32x32x16_bf16(V[0][c], pf, a0, 0, 0, 0);
      a1 = __builtin_amdgcn_mfma_f32_32x32x16_bf16(V[1][c], pf, a1, 0, 0, 0);
    }
  };

  for (int it = kv_lo; it < kv_hi; ++it) {
    bf16x8 K[2][4], V[2][4];
    loadkv(K, V, it * 64);
    compute(K, V, it * 64);
  }

  // ---- merge the two KV halves of each strip (half1 -> LDS, half0 merges)
  if (half) {
#pragma unroll
    for (int i = 0; i < 16; ++i) {
      sMrg[sb][lane][i] = a0[i];
      sMrg[sb][lane][16 + i] = a1[i];
    }
    sMrg[sb][lane][32] = m;
    sMrg[sb][lane][33] = l;
  }
  __syncthreads();
  if (!half) {
    const float mB = sMrg[sb][lane][32];
    const float lB = sMrg[sb][lane][33];
    const float ms = fmaxf(m, mB);
    const float fA = __builtin_amdgcn_exp2f(m - ms);
    const float fB = __builtin_amdgcn_exp2f(mB - ms);
    const float linv = 1.f / (l * fA + lB * fB);
    const size_t rowoff = ((size_t)(b * SEQN + qg)) * DMOD + h * DHEAD;
#pragma unroll
    for (int dblk = 0; dblk < 2; ++dblk) {
      const f32x16& av = dblk ? a1 : a0;
#pragma unroll
      for (int rg = 0; rg < 4; ++rg) {
        const int d0 = dblk * 32 + rg * 8 + 4 * hi;
        bf16x4 ov;
#pragma unroll
        for (int e = 0; e < 4; ++e)
          ov[e] = (bf16)((av[rg * 4 + e] * fA + sMrg[sb][lane][dblk * 16 + rg * 4 + e] * fB) * linv);
        *(bf16x4*)(AO + rowoff + d0) = ov;
      }
    }
  }
}

// ---------------------------------------------------------------- out gemm
__global__ __launch_bounds__(256) void gemm_out(
    const bf16* __restrict__ AO, const bf16* __restrict__ Wob,
    const float* __restrict__ bo, float* __restrict__ out)
{
  __shared__ bf16 sA[3][128 * 32];
  __shared__ bf16 sB[3][128 * 32];

  const int t = threadIdx.x;
  const int lane = t & 63, l15 = lane & 15, g = lane >> 4;
  const int wave = t >> 6, wm = wave >> 1, wn = wave & 1;
  const int tileM = blockIdx.y * 128, tileN = blockIdx.x * 128;

  f32x4 acc[4][4] = {};

  const bf16* gA = AO + (size_t)(tileM + (t >> 2)) * DMOD + (t & 3) * 8;
  const bf16* gB = Wob + (size_t)(tileN + (t >> 2)) * DMOD + (t & 3) * 8;

  auto stage = [&](int buf, int k0) {
    gload_lds16(gA + k0, &sA[buf][t * 8]);
    gload_lds16(gA + k0 + 64 * DMOD, &sA[buf][2048 + t * 8]);
    gload_lds16(gB + k0, &sB[buf][t * 8]);
    gload_lds16(gB + k0 + 64 * DMOD, &sB[buf][2048 + t * 8]);
  };

  stage(0, 0);
  stage(1, 32);

  const int NS = DMOD / 32;
  int cur = 0;
  for (int s = 0; s < NS; ++s) {
    if (s + 2 < NS) {
      int pf = cur + 2; if (pf >= 3) pf -= 3;
      stage(pf, (s + 2) * 32);
      asm volatile("s_waitcnt vmcnt(8)" ::: "memory");
    } else if (s + 1 < NS) {
      asm volatile("s_waitcnt vmcnt(4)" ::: "memory");
    } else {
      asm volatile("s_waitcnt vmcnt(0)" ::: "memory");
    }
    __builtin_amdgcn_s_barrier();
    asm volatile("" ::: "memory");

    const bf16* cA = sA[cur];
    const bf16* cB = sB[cur];
    bf16x8 af[4], bfr[4];
#pragma unroll
    for (int i = 0; i < 4; ++i)
      af[i] = *(const bf16x8*)(cA + (wm * 64 + i * 16 + l15) * 32 + g * 8);
#pragma unroll
    for (int j = 0; j < 4; ++j)
      bfr[j] = *(const bf16x8*)(cB + (wn * 64 + j * 16 + l15) * 32 + g * 8);
#pragma unroll
    for (int i = 0; i < 4; ++i)
#pragma unroll
      for (int j = 0; j < 4; ++j)
        acc[i][j] = __builtin_amdgcn_mfma_f32_16x16x32_bf16(af[i], bfr[j], acc[i][j], 0, 0, 0);

    asm volatile("" ::: "memory");
    __builtin_amdgcn_s_barrier();
    cur = (cur == 2) ? 0 : cur + 1;
  }

#pragma unroll
  for (int j = 0; j < 4; ++j) {
    const int col = tileN + wn * 64 + j * 16 + l15;
    const float bcol = bo[col];
#pragma unroll
    for (int i = 0; i < 4; ++i)
#pragma unroll
      for (int r = 0; r < 4; ++r) {
        const int row = tileM + wm * 64 + i * 16 + g * 4 + r;
        out[(size_t)row * DMOD + col] = acc[i][j][r] + bcol;
      }
  }
}

// ---------------------------------------------------------------- launch
extern "C" void kernel_launch(void* const* d_in, const int* in_sizes, int n_in,
                              void* d_out, int out_size, void* d_ws, size_t ws_size,
                              hipStream_t stream)
{
  (void)in_sizes; (void)n_in; (void)out_size; (void)ws_size;
  const float* X  = (const float*)d_in[0];
  const float* Wq = (const float*)d_in[1];
  const float* bq = (const float*)d_in[2];
  const float* Wk = (const float*)d_in[3];
  const float* bk = (const float*)d_in[4];
  const float* Wv = (const float*)d_in[5];
  const float* bv = (const float*)d_in[6];
  const float* Wo = (const float*)d_in[7];
  const float* bo = (const float*)d_in[8];

  char* ws = (char*)d_ws;
  float* ctab = (float*)(ws + 0);
  float* stab = (float*)(ws + 262144);
  bf16* Xb  = (bf16*)(ws + 524288);
  bf16* Wqb = (bf16*)(ws + 8912896);
  bf16* Wkb = (bf16*)(ws + 11010048);
  bf16* Wvb = (bf16*)(ws + 13107200);
  bf16* Wob = (bf16*)(ws + 15204352);
  bf16* Qb  = (bf16*)(ws + 17301504);
  bf16* Kb  = (bf16*)(ws + 25690112);
  bf16* Vtb = (bf16*)(ws + 34078720);   // 32*64*2080*2 = 8519680 bytes
  bf16* AO  = (bf16*)(ws + 42598400);

  prep_kernel<<<1024, 256, 0, stream>>>(X, Wq, Wk, Wv, Wo, Xb, Wqb, Wkb, Wvb, Wob, ctab, stab);
  gemm_qkv<<<dim3(8, 32, 3), 256, 0, stream>>>(Xb, Wqb, Wkb, Wvb, bq, bk, bv, ctab, stab, Qb, Kb, Vtb);
  attn_kernel<<<1024, 256, 0, stream>>>(Qb, Kb, Vtb, AO);
  gemm_out<<<dim3(8, 32), 256, 0, stream>>>(AO, Wob, bo, (float*)d_out);
}

// Round 12
// 146.593 us; speedup vs baseline: 1.0035x; 1.0035x over previous
//
#include <hip/hip_runtime.h>
#include <hip/hip_bf16.h>
#include <stdint.h>
#include <math.h>

// CausalMultiheadRoPEAttn: B=2, S=2048, D=1024, H=16, Dh=64
// prep (bf16 casts + rope table) -> fused QKV gemm (+bias+rope, V transposed,
// padded stride; counted-vmcnt depth-2 pipelined K-loop, raw barriers)
// -> flash attention: swapped-operand 32x32x16 MFMA, in-register softmax,
//    KV-split strips, zero-extra-register load rotation (K reloaded after
//    QK^T, V after PV), constant per-CU work decode, end-of-kernel LDS merge
// -> out gemm (pipelined K-loop).

typedef __bf16 bf16;
typedef __attribute__((ext_vector_type(4))) __bf16 bf16x4;
typedef __attribute__((ext_vector_type(8))) __bf16 bf16x8;
typedef __attribute__((ext_vector_type(4))) float f32x4;
typedef __attribute__((ext_vector_type(16))) float f32x16;
typedef __attribute__((ext_vector_type(4))) uint32_t u32x4;

#define SEQN 2048
#define DMOD 1024
#define NHEAD 16
#define DHEAD 64
#define MTOT 4096
#define VSTR 2080   // padded Vt row stride (elements)
// 0.125 * log2(e): scores land in log2 domain -> softmax uses exp2
#define QSCALE_LOG2E 0.18033688011112042f

__device__ __forceinline__ void gload_lds16(const bf16* g, bf16* l) {
  __builtin_amdgcn_global_load_lds(
      (const __attribute__((address_space(1))) uint32_t*)g,
      (__attribute__((address_space(3))) uint32_t*)l,
      16, 0, 0);
}

__device__ __forceinline__ uint32_t cvtpk(float lo, float hi) {
  uint32_t r;
  asm("v_cvt_pk_bf16_f32 %0, %1, %2" : "=v"(r) : "v"(lo), "v"(hi));
  return r;
}

// ---------------------------------------------------------------- prep
__global__ __launch_bounds__(256) void prep_kernel(
    const float* __restrict__ X,
    const float* __restrict__ Wq, const float* __restrict__ Wk,
    const float* __restrict__ Wv, const float* __restrict__ Wo,
    bf16* __restrict__ Xb, bf16* __restrict__ Wqb, bf16* __restrict__ Wkb,
    bf16* __restrict__ Wvb, bf16* __restrict__ Wob,
    float* __restrict__ ctab, float* __restrict__ stab)
{
  const int tid = blockIdx.x * blockDim.x + threadIdx.x;
  const int nth = gridDim.x * blockDim.x;

  const float4* X4 = (const float4*)X;
  for (int i = tid; i < MTOT * DMOD / 4; i += nth) {
    float4 v = X4[i];
    bf16x4 o = { (bf16)v.x, (bf16)v.y, (bf16)v.z, (bf16)v.w };
    *(bf16x4*)(Xb + (size_t)i * 4) = o;
  }
  const float4* q4 = (const float4*)Wq;
  const float4* k4 = (const float4*)Wk;
  const float4* v4 = (const float4*)Wv;
  const float4* o4 = (const float4*)Wo;
  for (int i = tid; i < DMOD * DMOD / 4; i += nth) {
    float4 a = q4[i];
    float4 b = k4[i];
    float4 c = v4[i];
    float4 d = o4[i];
    *(bf16x4*)(Wqb + (size_t)i * 4) = bf16x4{ (bf16)a.x, (bf16)a.y, (bf16)a.z, (bf16)a.w };
    *(bf16x4*)(Wkb + (size_t)i * 4) = bf16x4{ (bf16)b.x, (bf16)b.y, (bf16)b.z, (bf16)b.w };
    *(bf16x4*)(Wvb + (size_t)i * 4) = bf16x4{ (bf16)c.x, (bf16)c.y, (bf16)c.z, (bf16)c.w };
    *(bf16x4*)(Wob + (size_t)i * 4) = bf16x4{ (bf16)d.x, (bf16)d.y, (bf16)d.z, (bf16)d.w };
  }
  for (int i = tid; i < SEQN * 32; i += nth) {
    const int s = i >> 5, p = i & 31;
    const float invf = (float)pow(10000.0, -(double)p / 32.0);
    const float ang = (float)s * invf;
    float sv, cv;
    sincosf(ang, &sv, &cv);
    ctab[i] = cv;
    stab[i] = sv;
  }
}

// ---------------------------------------------------------------- QKV gemm
// 128x128 tile, BK=32, 3-buffer LDS pipeline with counted vmcnt: tile s+2's
// global_load_lds stay in flight across the barriers; raw s_barrier.
__global__ __launch_bounds__(256) void gemm_qkv(
    const bf16* __restrict__ Xb,
    const bf16* __restrict__ Wqb, const bf16* __restrict__ Wkb, const bf16* __restrict__ Wvb,
    const float* __restrict__ bq, const float* __restrict__ bk, const float* __restrict__ bv,
    const float* __restrict__ ctab, const float* __restrict__ stab,
    bf16* __restrict__ Qb, bf16* __restrict__ Kb, bf16* __restrict__ Vtb)
{
  __shared__ bf16 sA[3][128 * 32];
  __shared__ bf16 sB[3][128 * 32];

  const int z = blockIdx.z;
  const bf16* Bm = (z == 0) ? Wqb : (z == 1) ? Wkb : Wvb;
  const float* bias = (z == 0) ? bq : (z == 1) ? bk : bv;

  const int t = threadIdx.x;
  const int lane = t & 63, l15 = lane & 15, g = lane >> 4;
  const int wave = t >> 6, wm = wave >> 1, wn = wave & 1;
  const int tileM = blockIdx.y * 128, tileN = blockIdx.x * 128;

  f32x4 acc[4][4] = {};

  const bf16* gA = Xb + (size_t)(tileM + (t >> 2)) * DMOD + (t & 3) * 8;
  const bf16* gB = Bm + (size_t)(tileN + (t >> 2)) * DMOD + (t & 3) * 8;

  auto stage = [&](int buf, int k0) {
    gload_lds16(gA + k0, &sA[buf][t * 8]);
    gload_lds16(gA + k0 + 64 * DMOD, &sA[buf][2048 + t * 8]);
    gload_lds16(gB + k0, &sB[buf][t * 8]);
    gload_lds16(gB + k0 + 64 * DMOD, &sB[buf][2048 + t * 8]);
  };

  stage(0, 0);
  stage(1, 32);

  const int NS = DMOD / 32;   // 32 K-steps
  int cur = 0;
  for (int s = 0; s < NS; ++s) {
    if (s + 2 < NS) {
      int pf = cur + 2; if (pf >= 3) pf -= 3;
      stage(pf, (s + 2) * 32);
      asm volatile("s_waitcnt vmcnt(8)" ::: "memory");   // tile s landed
    } else if (s + 1 < NS) {
      asm volatile("s_waitcnt vmcnt(4)" ::: "memory");
    } else {
      asm volatile("s_waitcnt vmcnt(0)" ::: "memory");
    }
    __builtin_amdgcn_s_barrier();
    asm volatile("" ::: "memory");

    const bf16* cA = sA[cur];
    const bf16* cB = sB[cur];
    bf16x8 af[4], bfr[4];
#pragma unroll
    for (int i = 0; i < 4; ++i)
      af[i] = *(const bf16x8*)(cA + (wm * 64 + i * 16 + l15) * 32 + g * 8);
#pragma unroll
    for (int j = 0; j < 4; ++j)
      bfr[j] = *(const bf16x8*)(cB + (wn * 64 + j * 16 + l15) * 32 + g * 8);
#pragma unroll
    for (int i = 0; i < 4; ++i)
#pragma unroll
      for (int j = 0; j < 4; ++j)
        acc[i][j] = __builtin_amdgcn_mfma_f32_16x16x32_bf16(af[i], bfr[j], acc[i][j], 0, 0, 0);

    asm volatile("" ::: "memory");
    __builtin_amdgcn_s_barrier();   // buf `cur` free for reuse
    cur = (cur == 2) ? 0 : cur + 1;
  }

#pragma unroll
  for (int j = 0; j < 4; ++j) {
    const int col = tileN + wn * 64 + j * 16 + l15;
    const float bcol = bias[col];
    const int h = col >> 6, d = col & 63;
#pragma unroll
    for (int i = 0; i < 4; ++i) {
#pragma unroll
      for (int r = 0; r < 4; ++r) {
        const int row = tileM + wm * 64 + i * 16 + g * 4 + r;
        const int b = row >> 11, s = row & (SEQN - 1);
        const float v = acc[i][j][r] + bcol;
        if (z != 2) {
          const int pair = d >> 1;
          const float cv = ctab[s * 32 + pair];
          const float sv = stab[s * 32 + pair];
          const float partner = __shfl_xor(v, 1);
          float rv = (d & 1) ? (partner * sv + v * cv) : (v * cv - partner * sv);
          if (z == 0) rv *= QSCALE_LOG2E;   // fold softmax scale+log2e into Q
          bf16* dst = (z == 0) ? Qb : Kb;
          dst[(((size_t)(b * NHEAD + h)) * SEQN + s) * DHEAD + d] = (bf16)rv;
        } else {
          Vtb[(((size_t)(b * NHEAD + h)) * DHEAD + d) * VSTR + s] = (bf16)v;
        }
      }
    }
  }
}

// ---------------------------------------------------------------- attention
// 1024 blocks (32 strip-pairs x 32 bh; bid&31=bh -> XCD-local heads), 4 waves.
// Each 32-row strip is processed by TWO waves splitting its KV range in half
// (every wave <= 16 iters). Load rotation: K reloaded right after QK^T
// (hidden under softmax+PV), V reloaded right after PV (hidden under next
// QK^T+softmax) -> dbuf-grade hiding at zero extra VGPR. Boustrophedon jq
// decode: every CU's 4 resident blocks sum to identical work (round-robin
// heuristic). Swapped-operand 32x32x16 MFMA, in-register softmax, end-of-
// kernel LDS merge (half1 -> LDS, half0 merges+stores).
__global__ __launch_bounds__(256) void attn_kernel(
    const bf16* __restrict__ Qb, const bf16* __restrict__ Kb,
    const bf16* __restrict__ Vt, bf16* __restrict__ AO)
{
  __shared__ float sMrg[2][64][35];   // [strip_in_block][lane][a0(16),a1(16),m,l]

  const int t = threadIdx.x;
  const int lane = t & 63, l31 = lane & 31, hi = lane >> 5;
  const int wave = t >> 6;
  const int sb = wave >> 1;       // strip in block (0/1)
  const int half = wave & 1;      // 0: low KV half, 1: high KV half

  const int bid = blockIdx.x;
  const int bh = bid & 31;                 // bid%8 == bh%8
  const int grp = bid >> 8;                // 0..3 (round of 256)
  const int w = (bid >> 5) & 7;
  // per-256-group jq so each CU's 4 resident blocks sum to constant work:
  // g0: 31-w, g1: 16+w, g2: 15-w, g3: w  (covers 0..31 exactly)
  const int jq = (grp == 0) ? (31 - w) : (grp == 1) ? (16 + w)
               : (grp == 2) ? (15 - w) : w;
  const int qbase = (2 * jq + sb) * 32;
  const int qg = qbase + l31;              // this lane's q-row
  const int n = jq + 1;                    // KV-64 tiles covering the strip
  const int nA = (n + 1) >> 1;
  const int kv_lo = half ? nA : 0;
  const int kv_hi = half ? n : nA;

  const bf16* Kp = Kb + (size_t)bh * SEQN * DHEAD;
  const bf16* Vp = Vt + (size_t)bh * DHEAD * VSTR;
  const bf16* Qp = Qb + (size_t)bh * SEQN * DHEAD;
  const int b = bh >> 4, h = bh & 15;

  auto loadK = [&](bf16x8 (&K)[2][4], int kv0) {
#pragma unroll
    for (int s = 0; s < 2; ++s)
#pragma unroll
      for (int ch = 0; ch < 4; ++ch)
        K[s][ch] = *(const bf16x8*)(Kp + (size_t)(kv0 + 32 * s + l31) * DHEAD + 16 * ch + 8 * hi);
  };
  auto loadV = [&](bf16x8 (&V)[2][4], int kv0) {
#pragma unroll
    for (int dblk = 0; dblk < 2; ++dblk)
#pragma unroll
      for (int c = 0; c < 4; ++c)
        V[dblk][c] = *(const bf16x8*)(Vp + (size_t)(dblk * 32 + l31) * VSTR + kv0 + 16 * c + 8 * hi);
  };

  bf16x8 qf[4];   // Q B-frag: col=q=l31, k=8hi+e (d=16ch+8hi+e)
#pragma unroll
  for (int ch = 0; ch < 4; ++ch)
    qf[ch] = *(const bf16x8*)(Qp + (size_t)qg * DHEAD + 16 * ch + 8 * hi);

  f32x16 a0 = {}, a1 = {};
  float m = -1e30f, l = 0.f;

  if (kv_lo < kv_hi) {
    bf16x8 K[2][4], V[2][4];
    loadK(K, kv_lo * 64);
    loadV(V, kv_lo * 64);

    for (int it = kv_lo; it < kv_hi; ++it) {
      const int kv0 = it * 64;

      // ---- QK^T (consumes K)
      f32x16 s0 = {}, s1 = {};
#pragma unroll
      for (int ch = 0; ch < 4; ++ch) {
        s0 = __builtin_amdgcn_mfma_f32_32x32x16_bf16(K[0][ch], qf[ch], s0, 0, 0, 0);
        s1 = __builtin_amdgcn_mfma_f32_32x32x16_bf16(K[1][ch], qf[ch], s1, 0, 0, 0);
      }
      // K regs dead -> issue next tile's K loads; latency hides under
      // softmax + PV (~2000 cy)
      if (it + 1 < kv_hi) loadK(K, kv0 + 64);

      // tv[i]: score for key offset 32*(i>>4) + (i&3) + 8*((i>>2)&3) + 4*hi
      float tv[32];
#pragma unroll
      for (int i = 0; i < 16; ++i) { tv[i] = s0[i]; tv[16 + i] = s1[i]; }

      if (kv0 + 63 > qbase) {   // diagonal tile(s): causal mask (key > q)
#pragma unroll
        for (int i = 0; i < 32; ++i) {
          const int key = kv0 + 32 * (i >> 4) + ((i & 3) + 8 * ((i >> 2) & 3) + 4 * hi);
          if (key > qg) tv[i] = -1e30f;
        }
      }

      // row max: in-lane tree + cross-half shfl_xor(32)
      float red[16];
#pragma unroll
      for (int i = 0; i < 16; ++i) red[i] = fmaxf(tv[i], tv[i + 16]);
#pragma unroll
      for (int st = 8; st >= 1; st >>= 1)
#pragma unroll
        for (int i = 0; i < st; ++i) red[i] = fmaxf(red[i], red[i + st]);
      const float tmax = fmaxf(red[0], __shfl_xor(red[0], 32));
      const float mnew = fmaxf(m, tmax);
      const float alpha = __builtin_amdgcn_exp2f(m - mnew);
      m = mnew;

      // p = exp2(s - m), row sum
#pragma unroll
      for (int i = 0; i < 32; ++i) tv[i] = __builtin_amdgcn_exp2f(tv[i] - mnew);
#pragma unroll
      for (int i = 0; i < 16; ++i) red[i] = tv[i] + tv[i + 16];
#pragma unroll
      for (int st = 8; st >= 1; st >>= 1)
#pragma unroll
        for (int i = 0; i < st; ++i) red[i] += red[i + st];
      l = l * alpha + (red[0] + __shfl_xor(red[0], 32));

#pragma unroll
      for (int i = 0; i < 16; ++i) { a0[i] *= alpha; a1[i] *= alpha; }

      // P B-frag + PV (consumes V)
#pragma unroll
      for (int c = 0; c < 4; ++c) {
        const int b0 = (c & 1) * 8 + (c >> 1) * 16;   // base(2c); base(2c+1)=b0+4
        const uint32_t P0  = cvtpk(tv[b0 + 0], tv[b0 + 1]);
        const uint32_t P0b = cvtpk(tv[b0 + 2], tv[b0 + 3]);
        const uint32_t P1  = cvtpk(tv[b0 + 4], tv[b0 + 5]);
        const uint32_t P1b = cvtpk(tv[b0 + 6], tv[b0 + 7]);
        const uint32_t sP0  = (uint32_t)__shfl_xor((int)P0, 32);
        const uint32_t sP0b = (uint32_t)__shfl_xor((int)P0b, 32);
        const uint32_t sP1  = (uint32_t)__shfl_xor((int)P1, 32);
        const uint32_t sP1b = (uint32_t)__shfl_xor((int)P1b, 32);
        u32x4 pw;
        pw[0] = hi ? sP1  : P0;
        pw[1] = hi ? sP1b : P0b;
        pw[2] = hi ? P1   : sP0;
        pw[3] = hi ? P1b  : sP0b;
        const bf16x8 pf = __builtin_bit_cast(bf16x8, pw);
        a0 = __builtin_amdgcn_mfma_f32_32x32x16_bf16(V[0][c], pf, a0, 0, 0, 0);
        a1 = __builtin_amdgcn_mfma_f32_32x32x16_bf16(V[1][c], pf, a1, 0, 0, 0);
      }
      // V regs dead -> issue next tile's V loads; latency hides under the
      // next iteration's QK^T + softmax (~1500 cy)
      if (it + 1 < kv_hi) loadV(V, kv0 + 64);
    }
  }

  // ---- merge the two KV halves of each strip (half1 -> LDS, half0 merges)
  if (half) {
#pragma unroll
    for (int i = 0; i < 16; ++i) {
      sMrg[sb][lane][i] = a0[i];
      sMrg[sb][lane][16 + i] = a1[i];
    }
    sMrg[sb][lane][32] = m;
    sMrg[sb][lane][33] = l;
  }
  __syncthreads();
  if (!half) {
    const float mB = sMrg[sb][lane][32];
    const float lB = sMrg[sb][lane][33];
    const float ms = fmaxf(m, mB);
    const float fA = __builtin_amdgcn_exp2f(m - ms);
    const float fB = __builtin_amdgcn_exp2f(mB - ms);
    const float linv = 1.f / (l * fA + lB * fB);
    const size_t rowoff = ((size_t)(b * SEQN + qg)) * DMOD + h * DHEAD;
#pragma unroll
    for (int dblk = 0; dblk < 2; ++dblk) {
      const f32x16& av = dblk ? a1 : a0;
#pragma unroll
      for (int rg = 0; rg < 4; ++rg) {
        const int d0 = dblk * 32 + rg * 8 + 4 * hi;
        bf16x4 ov;
#pragma unroll
        for (int e = 0; e < 4; ++e)
          ov[e] = (bf16)((av[rg * 4 + e] * fA + sMrg[sb][lane][dblk * 16 + rg * 4 + e] * fB) * linv);
        *(bf16x4*)(AO + rowoff + d0) = ov;
      }
    }
  }
}

// ---------------------------------------------------------------- out gemm
__global__ __launch_bounds__(256) void gemm_out(
    const bf16* __restrict__ AO, const bf16* __restrict__ Wob,
    const float* __restrict__ bo, float* __restrict__ out)
{
  __shared__ bf16 sA[3][128 * 32];
  __shared__ bf16 sB[3][128 * 32];

  const int t = threadIdx.x;
  const int lane = t & 63, l15 = lane & 15, g = lane >> 4;
  const int wave = t >> 6, wm = wave >> 1, wn = wave & 1;
  const int tileM = blockIdx.y * 128, tileN = blockIdx.x * 128;

  f32x4 acc[4][4] = {};

  const bf16* gA = AO + (size_t)(tileM + (t >> 2)) * DMOD + (t & 3) * 8;
  const bf16* gB = Wob + (size_t)(tileN + (t >> 2)) * DMOD + (t & 3) * 8;

  auto stage = [&](int buf, int k0) {
    gload_lds16(gA + k0, &sA[buf][t * 8]);
    gload_lds16(gA + k0 + 64 * DMOD, &sA[buf][2048 + t * 8]);
    gload_lds16(gB + k0, &sB[buf][t * 8]);
    gload_lds16(gB + k0 + 64 * DMOD, &sB[buf][2048 + t * 8]);
  };

  stage(0, 0);
  stage(1, 32);

  const int NS = DMOD / 32;
  int cur = 0;
  for (int s = 0; s < NS; ++s) {
    if (s + 2 < NS) {
      int pf = cur + 2; if (pf >= 3) pf -= 3;
      stage(pf, (s + 2) * 32);
      asm volatile("s_waitcnt vmcnt(8)" ::: "memory");
    } else if (s + 1 < NS) {
      asm volatile("s_waitcnt vmcnt(4)" ::: "memory");
    } else {
      asm volatile("s_waitcnt vmcnt(0)" ::: "memory");
    }
    __builtin_amdgcn_s_barrier();
    asm volatile("" ::: "memory");

    const bf16* cA = sA[cur];
    const bf16* cB = sB[cur];
    bf16x8 af[4], bfr[4];
#pragma unroll
    for (int i = 0; i < 4; ++i)
      af[i] = *(const bf16x8*)(cA + (wm * 64 + i * 16 + l15) * 32 + g * 8);
#pragma unroll
    for (int j = 0; j < 4; ++j)
      bfr[j] = *(const bf16x8*)(cB + (wn * 64 + j * 16 + l15) * 32 + g * 8);
#pragma unroll
    for (int i = 0; i < 4; ++i)
#pragma unroll
      for (int j = 0; j < 4; ++j)
        acc[i][j] = __builtin_amdgcn_mfma_f32_16x16x32_bf16(af[i], bfr[j], acc[i][j], 0, 0, 0);

    asm volatile("" ::: "memory");
    __builtin_amdgcn_s_barrier();
    cur = (cur == 2) ? 0 : cur + 1;
  }

#pragma unroll
  for (int j = 0; j < 4; ++j) {
    const int col = tileN + wn * 64 + j * 16 + l15;
    const float bcol = bo[col];
#pragma unroll
    for (int i = 0; i < 4; ++i)
#pragma unroll
      for (int r = 0; r < 4; ++r) {
        const int row = tileM + wm * 64 + i * 16 + g * 4 + r;
        out[(size_t)row * DMOD + col] = acc[i][j][r] + bcol;
      }
  }
}

// ---------------------------------------------------------------- launch
extern "C" void kernel_launch(void* const* d_in, const int* in_sizes, int n_in,
                              void* d_out, int out_size, void* d_ws, size_t ws_size,
                              hipStream_t stream)
{
  (void)in_sizes; (void)n_in; (void)out_size; (void)ws_size;
  const float* X  = (const float*)d_in[0];
  const float* Wq = (const float*)d_in[1];
  const float* bq = (const float*)d_in[2];
  const float* Wk = (const float*)d_in[3];
  const float* bk = (const float*)d_in[4];
  const float* Wv = (const float*)d_in[5];
  const float* bv = (const float*)d_in[6];
  const float* Wo = (const float*)d_in[7];
  const float* bo = (const float*)d_in[8];

  char* ws = (char*)d_ws;
  float* ctab = (float*)(ws + 0);
  float* stab = (float*)(ws + 262144);
  bf16* Xb  = (bf16*)(ws + 524288);
  bf16* Wqb = (bf16*)(ws + 8912896);
  bf16* Wkb = (bf16*)(ws + 11010048);
  bf16* Wvb = (bf16*)(ws + 13107200);
  bf16* Wob = (bf16*)(ws + 15204352);
  bf16* Qb  = (bf16*)(ws + 17301504);
  bf16* Kb  = (bf16*)(ws + 25690112);
  bf16* Vtb = (bf16*)(ws + 34078720);   // 32*64*2080*2 = 8519680 bytes
  bf16* AO  = (bf16*)(ws + 42598400);

  prep_kernel<<<1024, 256, 0, stream>>>(X, Wq, Wk, Wv, Wo, Xb, Wqb, Wkb, Wvb, Wob, ctab, stab);
  gemm_qkv<<<dim3(8, 32, 3), 256, 0, stream>>>(Xb, Wqb, Wkb, Wvb, bq, bk, bv, ctab, stab, Qb, Kb, Vtb);
  attn_kernel<<<1024, 256, 0, stream>>>(Qb, Kb, Vtb, AO);
  gemm_out<<<dim3(8, 32), 256, 0, stream>>>(AO, Wob, bo, (float*)d_out);
}

// Round 13
// 146.192 us; speedup vs baseline: 1.0062x; 1.0027x over previous
//
#include <hip/hip_runtime.h>
#include <hip/hip_bf16.h>
#include <stdint.h>
#include <math.h>

// CausalMultiheadRoPEAttn: B=2, S=2048, D=1024, H=16, Dh=64
// prep (bf16 casts + rope table) -> fused QKV gemm (+bias+rope, V transposed,
// padded stride; counted-vmcnt depth-2 pipelined K-loop, raw barriers)
// -> flash attention: swapped-operand 32x32x16 MFMA, in-register softmax
//    with DEFER-MAX (THR=8, log2 domain) + per-half l accumulation (zero
//    per-iter cross-half shuffles in steady state), KV-split strips, load
//    rotation, setprio around MFMA, end-of-kernel LDS merge
// -> out gemm (pipelined K-loop).

typedef __bf16 bf16;
typedef __attribute__((ext_vector_type(4))) __bf16 bf16x4;
typedef __attribute__((ext_vector_type(8))) __bf16 bf16x8;
typedef __attribute__((ext_vector_type(4))) float f32x4;
typedef __attribute__((ext_vector_type(16))) float f32x16;
typedef __attribute__((ext_vector_type(4))) uint32_t u32x4;

#define SEQN 2048
#define DMOD 1024
#define NHEAD 16
#define DHEAD 64
#define MTOT 4096
#define VSTR 2080   // padded Vt row stride (elements)
// 0.125 * log2(e): scores land in log2 domain -> softmax uses exp2
#define QSCALE_LOG2E 0.18033688011112042f
#define DEFER_THR 8.0f   // exp2(8)=256 max P magnitude; uniform, cancels in /l

__device__ __forceinline__ void gload_lds16(const bf16* g, bf16* l) {
  __builtin_amdgcn_global_load_lds(
      (const __attribute__((address_space(1))) uint32_t*)g,
      (__attribute__((address_space(3))) uint32_t*)l,
      16, 0, 0);
}

__device__ __forceinline__ uint32_t cvtpk(float lo, float hi) {
  uint32_t r;
  asm("v_cvt_pk_bf16_f32 %0, %1, %2" : "=v"(r) : "v"(lo), "v"(hi));
  return r;
}

// ---------------------------------------------------------------- prep
__global__ __launch_bounds__(256) void prep_kernel(
    const float* __restrict__ X,
    const float* __restrict__ Wq, const float* __restrict__ Wk,
    const float* __restrict__ Wv, const float* __restrict__ Wo,
    bf16* __restrict__ Xb, bf16* __restrict__ Wqb, bf16* __restrict__ Wkb,
    bf16* __restrict__ Wvb, bf16* __restrict__ Wob,
    float* __restrict__ ctab, float* __restrict__ stab)
{
  const int tid = blockIdx.x * blockDim.x + threadIdx.x;
  const int nth = gridDim.x * blockDim.x;

  const float4* X4 = (const float4*)X;
  for (int i = tid; i < MTOT * DMOD / 4; i += nth) {
    float4 v = X4[i];
    bf16x4 o = { (bf16)v.x, (bf16)v.y, (bf16)v.z, (bf16)v.w };
    *(bf16x4*)(Xb + (size_t)i * 4) = o;
  }
  const float4* q4 = (const float4*)Wq;
  const float4* k4 = (const float4*)Wk;
  const float4* v4 = (const float4*)Wv;
  const float4* o4 = (const float4*)Wo;
  for (int i = tid; i < DMOD * DMOD / 4; i += nth) {
    float4 a = q4[i];
    float4 b = k4[i];
    float4 c = v4[i];
    float4 d = o4[i];
    *(bf16x4*)(Wqb + (size_t)i * 4) = bf16x4{ (bf16)a.x, (bf16)a.y, (bf16)a.z, (bf16)a.w };
    *(bf16x4*)(Wkb + (size_t)i * 4) = bf16x4{ (bf16)b.x, (bf16)b.y, (bf16)b.z, (bf16)b.w };
    *(bf16x4*)(Wvb + (size_t)i * 4) = bf16x4{ (bf16)c.x, (bf16)c.y, (bf16)c.z, (bf16)c.w };
    *(bf16x4*)(Wob + (size_t)i * 4) = bf16x4{ (bf16)d.x, (bf16)d.y, (bf16)d.z, (bf16)d.w };
  }
  for (int i = tid; i < SEQN * 32; i += nth) {
    const int s = i >> 5, p = i & 31;
    const float invf = (float)pow(10000.0, -(double)p / 32.0);
    const float ang = (float)s * invf;
    float sv, cv;
    sincosf(ang, &sv, &cv);
    ctab[i] = cv;
    stab[i] = sv;
  }
}

// ---------------------------------------------------------------- QKV gemm
// 128x128 tile, BK=32, 3-buffer LDS pipeline with counted vmcnt: tile s+2's
// global_load_lds stay in flight across the barriers; raw s_barrier.
__global__ __launch_bounds__(256) void gemm_qkv(
    const bf16* __restrict__ Xb,
    const bf16* __restrict__ Wqb, const bf16* __restrict__ Wkb, const bf16* __restrict__ Wvb,
    const float* __restrict__ bq, const float* __restrict__ bk, const float* __restrict__ bv,
    const float* __restrict__ ctab, const float* __restrict__ stab,
    bf16* __restrict__ Qb, bf16* __restrict__ Kb, bf16* __restrict__ Vtb)
{
  __shared__ bf16 sA[3][128 * 32];
  __shared__ bf16 sB[3][128 * 32];

  const int z = blockIdx.z;
  const bf16* Bm = (z == 0) ? Wqb : (z == 1) ? Wkb : Wvb;
  const float* bias = (z == 0) ? bq : (z == 1) ? bk : bv;

  const int t = threadIdx.x;
  const int lane = t & 63, l15 = lane & 15, g = lane >> 4;
  const int wave = t >> 6, wm = wave >> 1, wn = wave & 1;
  const int tileM = blockIdx.y * 128, tileN = blockIdx.x * 128;

  f32x4 acc[4][4] = {};

  const bf16* gA = Xb + (size_t)(tileM + (t >> 2)) * DMOD + (t & 3) * 8;
  const bf16* gB = Bm + (size_t)(tileN + (t >> 2)) * DMOD + (t & 3) * 8;

  auto stage = [&](int buf, int k0) {
    gload_lds16(gA + k0, &sA[buf][t * 8]);
    gload_lds16(gA + k0 + 64 * DMOD, &sA[buf][2048 + t * 8]);
    gload_lds16(gB + k0, &sB[buf][t * 8]);
    gload_lds16(gB + k0 + 64 * DMOD, &sB[buf][2048 + t * 8]);
  };

  stage(0, 0);
  stage(1, 32);

  const int NS = DMOD / 32;   // 32 K-steps
  int cur = 0;
  for (int s = 0; s < NS; ++s) {
    if (s + 2 < NS) {
      int pf = cur + 2; if (pf >= 3) pf -= 3;
      stage(pf, (s + 2) * 32);
      asm volatile("s_waitcnt vmcnt(8)" ::: "memory");   // tile s landed
    } else if (s + 1 < NS) {
      asm volatile("s_waitcnt vmcnt(4)" ::: "memory");
    } else {
      asm volatile("s_waitcnt vmcnt(0)" ::: "memory");
    }
    __builtin_amdgcn_s_barrier();
    asm volatile("" ::: "memory");

    const bf16* cA = sA[cur];
    const bf16* cB = sB[cur];
    bf16x8 af[4], bfr[4];
#pragma unroll
    for (int i = 0; i < 4; ++i)
      af[i] = *(const bf16x8*)(cA + (wm * 64 + i * 16 + l15) * 32 + g * 8);
#pragma unroll
    for (int j = 0; j < 4; ++j)
      bfr[j] = *(const bf16x8*)(cB + (wn * 64 + j * 16 + l15) * 32 + g * 8);
#pragma unroll
    for (int i = 0; i < 4; ++i)
#pragma unroll
      for (int j = 0; j < 4; ++j)
        acc[i][j] = __builtin_amdgcn_mfma_f32_16x16x32_bf16(af[i], bfr[j], acc[i][j], 0, 0, 0);

    asm volatile("" ::: "memory");
    __builtin_amdgcn_s_barrier();   // buf `cur` free for reuse
    cur = (cur == 2) ? 0 : cur + 1;
  }

#pragma unroll
  for (int j = 0; j < 4; ++j) {
    const int col = tileN + wn * 64 + j * 16 + l15;
    const float bcol = bias[col];
    const int h = col >> 6, d = col & 63;
#pragma unroll
    for (int i = 0; i < 4; ++i) {
#pragma unroll
      for (int r = 0; r < 4; ++r) {
        const int row = tileM + wm * 64 + i * 16 + g * 4 + r;
        const int b = row >> 11, s = row & (SEQN - 1);
        const float v = acc[i][j][r] + bcol;
        if (z != 2) {
          const int pair = d >> 1;
          const float cv = ctab[s * 32 + pair];
          const float sv = stab[s * 32 + pair];
          const float partner = __shfl_xor(v, 1);
          float rv = (d & 1) ? (partner * sv + v * cv) : (v * cv - partner * sv);
          if (z == 0) rv *= QSCALE_LOG2E;   // fold softmax scale+log2e into Q
          bf16* dst = (z == 0) ? Qb : Kb;
          dst[(((size_t)(b * NHEAD + h)) * SEQN + s) * DHEAD + d] = (bf16)rv;
        } else {
          Vtb[(((size_t)(b * NHEAD + h)) * DHEAD + d) * VSTR + s] = (bf16)v;
        }
      }
    }
  }
}

// ---------------------------------------------------------------- attention
// 1024 blocks (32 strip-pairs x 32 bh; bid&31=bh -> XCD-local heads), 4 waves.
// Each 32-row strip split across two waves (KV halves). Per-iter softmax has
// ZERO cross-half shuffles in steady state: l accumulated per-lane over own
// 32 keys (combined once at end); max deferred (THR=8 log2) behind a wave-
// uniform __any branch that synchronizes m across partner lanes when taken.
// K reloaded after QK^T, V after PV (latency hidden, +0 VGPR). setprio(1)
// around MFMA clusters. End-of-kernel LDS merge (half1 -> LDS, half0 stores).
__global__ __launch_bounds__(256) void attn_kernel(
    const bf16* __restrict__ Qb, const bf16* __restrict__ Kb,
    const bf16* __restrict__ Vt, bf16* __restrict__ AO)
{
  __shared__ float sMrg[2][64][35];   // [strip_in_block][lane][a0(16),a1(16),m,l]

  const int t = threadIdx.x;
  const int lane = t & 63, l31 = lane & 31, hi = lane >> 5;
  const int wave = t >> 6;
  const int sb = wave >> 1;       // strip in block (0/1)
  const int half = wave & 1;      // 0: low KV half, 1: high KV half

  const int bid = blockIdx.x;
  const int bh = bid & 31;                 // bid%8 == bh%8
  const int grp = bid >> 8;                // 0..3 (round of 256)
  const int w = (bid >> 5) & 7;
  const int jq = (grp == 0) ? (31 - w) : (grp == 1) ? (16 + w)
               : (grp == 2) ? (15 - w) : w;
  const int qbase = (2 * jq + sb) * 32;
  const int qg = qbase + l31;              // this lane's q-row
  const int n = jq + 1;                    // KV-64 tiles covering the strip
  const int nA = (n + 1) >> 1;
  const int kv_lo = half ? nA : 0;
  const int kv_hi = half ? n : nA;

  const bf16* Kp = Kb + (size_t)bh * SEQN * DHEAD;
  const bf16* Vp = Vt + (size_t)bh * DHEAD * VSTR;
  const bf16* Qp = Qb + (size_t)bh * SEQN * DHEAD;
  const int b = bh >> 4, h = bh & 15;

  auto loadK = [&](bf16x8 (&K)[2][4], int kv0) {
#pragma unroll
    for (int s = 0; s < 2; ++s)
#pragma unroll
      for (int ch = 0; ch < 4; ++ch)
        K[s][ch] = *(const bf16x8*)(Kp + (size_t)(kv0 + 32 * s + l31) * DHEAD + 16 * ch + 8 * hi);
  };
  auto loadV = [&](bf16x8 (&V)[2][4], int kv0) {
#pragma unroll
    for (int dblk = 0; dblk < 2; ++dblk)
#pragma unroll
      for (int c = 0; c < 4; ++c)
        V[dblk][c] = *(const bf16x8*)(Vp + (size_t)(dblk * 32 + l31) * VSTR + kv0 + 16 * c + 8 * hi);
  };

  bf16x8 qf[4];   // Q B-frag: col=q=l31, k=8hi+e (d=16ch+8hi+e)
#pragma unroll
  for (int ch = 0; ch < 4; ++ch)
    qf[ch] = *(const bf16x8*)(Qp + (size_t)qg * DHEAD + 16 * ch + 8 * hi);

  f32x16 a0 = {}, a1 = {};
  float m = -1e30f, l = 0.f;   // l: per-lane over OWN 32 keys; full row at end

  if (kv_lo < kv_hi) {
    bf16x8 K[2][4], V[2][4];
    loadK(K, kv_lo * 64);
    loadV(V, kv_lo * 64);

    for (int it = kv_lo; it < kv_hi; ++it) {
      const int kv0 = it * 64;

      // ---- QK^T (consumes K)
      f32x16 s0 = {}, s1 = {};
      __builtin_amdgcn_s_setprio(1);
#pragma unroll
      for (int ch = 0; ch < 4; ++ch) {
        s0 = __builtin_amdgcn_mfma_f32_32x32x16_bf16(K[0][ch], qf[ch], s0, 0, 0, 0);
        s1 = __builtin_amdgcn_mfma_f32_32x32x16_bf16(K[1][ch], qf[ch], s1, 0, 0, 0);
      }
      __builtin_amdgcn_s_setprio(0);
      if (it + 1 < kv_hi) loadK(K, kv0 + 64);   // hides under softmax+PV

      // tv[i]: score for key offset 32*(i>>4) + (i&3) + 8*((i>>2)&3) + 4*hi
      float tv[32];
#pragma unroll
      for (int i = 0; i < 16; ++i) { tv[i] = s0[i]; tv[16 + i] = s1[i]; }

      if (kv0 + 63 > qbase) {   // diagonal tile(s): causal mask (key > q)
#pragma unroll
        for (int i = 0; i < 32; ++i) {
          const int key = kv0 + 32 * (i >> 4) + ((i & 3) + 8 * ((i >> 2) & 3) + 4 * hi);
          if (key > qg) tv[i] = -1e30f;
        }
      }

      // own-half max tree (no cross-half shuffle in steady state)
      float red[16];
#pragma unroll
      for (int i = 0; i < 16; ++i) red[i] = fmaxf(tv[i], tv[i + 16]);
#pragma unroll
      for (int st = 8; st >= 1; st >>= 1)
#pragma unroll
        for (int i = 0; i < st; ++i) red[i] = fmaxf(red[i], red[i + st]);
      const float tmax_own = red[0];

      // defer-max: only rescale when some lane's half-max exceeds m+THR.
      // Branch is wave-uniform; the in-branch shuffle synchronizes m across
      // partner lanes (incl. the all-masked-half case).
      if (__any(tmax_own > m + DEFER_THR)) {
        const float tfull = fmaxf(tmax_own, __shfl_xor(tmax_own, 32));
        const float mnew = fmaxf(m, tfull);
        const float alpha = __builtin_amdgcn_exp2f(m - mnew);
        m = mnew;
        l *= alpha;
#pragma unroll
        for (int i = 0; i < 16; ++i) { a0[i] *= alpha; a1[i] *= alpha; }
      }

      // p = exp2(s - m) (bounded by 2^THR); per-lane sum over own keys
#pragma unroll
      for (int i = 0; i < 32; ++i) tv[i] = __builtin_amdgcn_exp2f(tv[i] - m);
#pragma unroll
      for (int i = 0; i < 16; ++i) red[i] = tv[i] + tv[i + 16];
#pragma unroll
      for (int st = 8; st >= 1; st >>= 1)
#pragma unroll
        for (int i = 0; i < st; ++i) red[i] += red[i + st];
      l += red[0];

      // P B-frag + PV (consumes V)
      __builtin_amdgcn_s_setprio(1);
#pragma unroll
      for (int c = 0; c < 4; ++c) {
        const int b0 = (c & 1) * 8 + (c >> 1) * 16;   // base(2c); base(2c+1)=b0+4
        const uint32_t P0  = cvtpk(tv[b0 + 0], tv[b0 + 1]);
        const uint32_t P0b = cvtpk(tv[b0 + 2], tv[b0 + 3]);
        const uint32_t P1  = cvtpk(tv[b0 + 4], tv[b0 + 5]);
        const uint32_t P1b = cvtpk(tv[b0 + 6], tv[b0 + 7]);
        const uint32_t sP0  = (uint32_t)__shfl_xor((int)P0, 32);
        const uint32_t sP0b = (uint32_t)__shfl_xor((int)P0b, 32);
        const uint32_t sP1  = (uint32_t)__shfl_xor((int)P1, 32);
        const uint32_t sP1b = (uint32_t)__shfl_xor((int)P1b, 32);
        u32x4 pw;
        pw[0] = hi ? sP1  : P0;
        pw[1] = hi ? sP1b : P0b;
        pw[2] = hi ? P1   : sP0;
        pw[3] = hi ? P1b  : sP0b;
        const bf16x8 pf = __builtin_bit_cast(bf16x8, pw);
        a0 = __builtin_amdgcn_mfma_f32_32x32x16_bf16(V[0][c], pf, a0, 0, 0, 0);
        a1 = __builtin_amdgcn_mfma_f32_32x32x16_bf16(V[1][c], pf, a1, 0, 0, 0);
      }
      __builtin_amdgcn_s_setprio(0);
      if (it + 1 < kv_hi) loadV(V, kv0 + 64);   // hides under next QK^T
    }
  }

  // full-row l for this wave's kv range (one shuffle, once)
  const float l_full = l + __shfl_xor(l, 32);

  // ---- merge the two KV halves of each strip (half1 -> LDS, half0 merges)
  if (half) {
#pragma unroll
    for (int i = 0; i < 16; ++i) {
      sMrg[sb][lane][i] = a0[i];
      sMrg[sb][lane][16 + i] = a1[i];
    }
    sMrg[sb][lane][32] = m;
    sMrg[sb][lane][33] = l_full;
  }
  __syncthreads();
  if (!half) {
    const float mB = sMrg[sb][lane][32];
    const float lB = sMrg[sb][lane][33];
    const float ms = fmaxf(m, mB);
    const float fA = __builtin_amdgcn_exp2f(m - ms);
    const float fB = __builtin_amdgcn_exp2f(mB - ms);
    const float linv = 1.f / (l_full * fA + lB * fB);
    const size_t rowoff = ((size_t)(b * SEQN + qg)) * DMOD + h * DHEAD;
#pragma unroll
    for (int dblk = 0; dblk < 2; ++dblk) {
      const f32x16& av = dblk ? a1 : a0;
#pragma unroll
      for (int rg = 0; rg < 4; ++rg) {
        const int d0 = dblk * 32 + rg * 8 + 4 * hi;
        bf16x4 ov;
#pragma unroll
        for (int e = 0; e < 4; ++e)
          ov[e] = (bf16)((av[rg * 4 + e] * fA + sMrg[sb][lane][dblk * 16 + rg * 4 + e] * fB) * linv);
        *(bf16x4*)(AO + rowoff + d0) = ov;
      }
    }
  }
}

// ---------------------------------------------------------------- out gemm
__global__ __launch_bounds__(256) void gemm_out(
    const bf16* __restrict__ AO, const bf16* __restrict__ Wob,
    const float* __restrict__ bo, float* __restrict__ out)
{
  __shared__ bf16 sA[3][128 * 32];
  __shared__ bf16 sB[3][128 * 32];

  const int t = threadIdx.x;
  const int lane = t & 63, l15 = lane & 15, g = lane >> 4;
  const int wave = t >> 6, wm = wave >> 1, wn = wave & 1;
  const int tileM = blockIdx.y * 128, tileN = blockIdx.x * 128;

  f32x4 acc[4][4] = {};

  const bf16* gA = AO + (size_t)(tileM + (t >> 2)) * DMOD + (t & 3) * 8;
  const bf16* gB = Wob + (size_t)(tileN + (t >> 2)) * DMOD + (t & 3) * 8;

  auto stage = [&](int buf, int k0) {
    gload_lds16(gA + k0, &sA[buf][t * 8]);
    gload_lds16(gA + k0 + 64 * DMOD, &sA[buf][2048 + t * 8]);
    gload_lds16(gB + k0, &sB[buf][t * 8]);
    gload_lds16(gB + k0 + 64 * DMOD, &sB[buf][2048 + t * 8]);
  };

  stage(0, 0);
  stage(1, 32);

  const int NS = DMOD / 32;
  int cur = 0;
  for (int s = 0; s < NS; ++s) {
    if (s + 2 < NS) {
      int pf = cur + 2; if (pf >= 3) pf -= 3;
      stage(pf, (s + 2) * 32);
      asm volatile("s_waitcnt vmcnt(8)" ::: "memory");
    } else if (s + 1 < NS) {
      asm volatile("s_waitcnt vmcnt(4)" ::: "memory");
    } else {
      asm volatile("s_waitcnt vmcnt(0)" ::: "memory");
    }
    __builtin_amdgcn_s_barrier();
    asm volatile("" ::: "memory");

    const bf16* cA = sA[cur];
    const bf16* cB = sB[cur];
    bf16x8 af[4], bfr[4];
#pragma unroll
    for (int i = 0; i < 4; ++i)
      af[i] = *(const bf16x8*)(cA + (wm * 64 + i * 16 + l15) * 32 + g * 8);
#pragma unroll
    for (int j = 0; j < 4; ++j)
      bfr[j] = *(const bf16x8*)(cB + (wn * 64 + j * 16 + l15) * 32 + g * 8);
#pragma unroll
    for (int i = 0; i < 4; ++i)
#pragma unroll
      for (int j = 0; j < 4; ++j)
        acc[i][j] = __builtin_amdgcn_mfma_f32_16x16x32_bf16(af[i], bfr[j], acc[i][j], 0, 0, 0);

    asm volatile("" ::: "memory");
    __builtin_amdgcn_s_barrier();
    cur = (cur == 2) ? 0 : cur + 1;
  }

#pragma unroll
  for (int j = 0; j < 4; ++j) {
    const int col = tileN + wn * 64 + j * 16 + l15;
    const float bcol = bo[col];
#pragma unroll
    for (int i = 0; i < 4; ++i)
#pragma unroll
      for (int r = 0; r < 4; ++r) {
        const int row = tileM + wm * 64 + i * 16 + g * 4 + r;
        out[(size_t)row * DMOD + col] = acc[i][j][r] + bcol;
      }
  }
}

// ---------------------------------------------------------------- launch
extern "C" void kernel_launch(void* const* d_in, const int* in_sizes, int n_in,
                              void* d_out, int out_size, void* d_ws, size_t ws_size,
                              hipStream_t stream)
{
  (void)in_sizes; (void)n_in; (void)out_size; (void)ws_size;
  const float* X  = (const float*)d_in[0];
  const float* Wq = (const float*)d_in[1];
  const float* bq = (const float*)d_in[2];
  const float* Wk = (const float*)d_in[3];
  const float* bk = (const float*)d_in[4];
  const float* Wv = (const float*)d_in[5];
  const float* bv = (const float*)d_in[6];
  const float* Wo = (const float*)d_in[7];
  const float* bo = (const float*)d_in[8];

  char* ws = (char*)d_ws;
  float* ctab = (float*)(ws + 0);
  float* stab = (float*)(ws + 262144);
  bf16* Xb  = (bf16*)(ws + 524288);
  bf16* Wqb = (bf16*)(ws + 8912896);
  bf16* Wkb = (bf16*)(ws + 11010048);
  bf16* Wvb = (bf16*)(ws + 13107200);
  bf16* Wob = (bf16*)(ws + 15204352);
  bf16* Qb  = (bf16*)(ws + 17301504);
  bf16* Kb  = (bf16*)(ws + 25690112);
  bf16* Vtb = (bf16*)(ws + 34078720);   // 32*64*2080*2 = 8519680 bytes
  bf16* AO  = (bf16*)(ws + 42598400);

  prep_kernel<<<1024, 256, 0, stream>>>(X, Wq, Wk, Wv, Wo, Xb, Wqb, Wkb, Wvb, Wob, ctab, stab);
  gemm_qkv<<<dim3(8, 32, 3), 256, 0, stream>>>(Xb, Wqb, Wkb, Wvb, bq, bk, bv, ctab, stab, Qb, Kb, Vtb);
  attn_kernel<<<1024, 256, 0, stream>>>(Qb, Kb, Vtb, AO);
  gemm_out<<<dim3(8, 32), 256, 0, stream>>>(AO, Wob, bo, (float*)d_out);
}

// Round 14
// 144.028 us; speedup vs baseline: 1.0213x; 1.0150x over previous
//
#include <hip/hip_runtime.h>
#include <hip/hip_bf16.h>
#include <stdint.h>
#include <math.h>

// CausalMultiheadRoPEAttn: B=2, S=2048, D=1024, H=16, Dh=64
// prep (bf16 casts + rope table) -> fused QKV gemm (+bias+rope, V transposed,
// padded stride; counted-vmcnt depth-2 pipelined K-loop, raw barriers)
// -> flash attention: swapped-operand 32x32x16 MFMA, KVBLK=32 register-diet
//    (live set fits VGPRs -> no AGPR shuttling), in-place in-register softmax
//    with defer-max, KV-split strips, load rotation, end-of-kernel LDS merge
// -> out gemm (pipelined K-loop).

typedef __bf16 bf16;
typedef __attribute__((ext_vector_type(4))) __bf16 bf16x4;
typedef __attribute__((ext_vector_type(8))) __bf16 bf16x8;
typedef __attribute__((ext_vector_type(4))) float f32x4;
typedef __attribute__((ext_vector_type(16))) float f32x16;
typedef __attribute__((ext_vector_type(4))) uint32_t u32x4;

#define SEQN 2048
#define DMOD 1024
#define NHEAD 16
#define DHEAD 64
#define MTOT 4096
#define VSTR 2080   // padded Vt row stride (elements)
// 0.125 * log2(e): scores land in log2 domain -> softmax uses exp2
#define QSCALE_LOG2E 0.18033688011112042f
#define DEFER_THR 8.0f   // exp2(8)=256 max P magnitude; uniform, cancels in /l

__device__ __forceinline__ void gload_lds16(const bf16* g, bf16* l) {
  __builtin_amdgcn_global_load_lds(
      (const __attribute__((address_space(1))) uint32_t*)g,
      (__attribute__((address_space(3))) uint32_t*)l,
      16, 0, 0);
}

__device__ __forceinline__ uint32_t cvtpk(float lo, float hi) {
  uint32_t r;
  asm("v_cvt_pk_bf16_f32 %0, %1, %2" : "=v"(r) : "v"(lo), "v"(hi));
  return r;
}

// ---------------------------------------------------------------- prep
__global__ __launch_bounds__(256) void prep_kernel(
    const float* __restrict__ X,
    const float* __restrict__ Wq, const float* __restrict__ Wk,
    const float* __restrict__ Wv, const float* __restrict__ Wo,
    bf16* __restrict__ Xb, bf16* __restrict__ Wqb, bf16* __restrict__ Wkb,
    bf16* __restrict__ Wvb, bf16* __restrict__ Wob,
    float* __restrict__ ctab, float* __restrict__ stab)
{
  const int tid = blockIdx.x * blockDim.x + threadIdx.x;
  const int nth = gridDim.x * blockDim.x;

  const float4* X4 = (const float4*)X;
  for (int i = tid; i < MTOT * DMOD / 4; i += nth) {
    float4 v = X4[i];
    bf16x4 o = { (bf16)v.x, (bf16)v.y, (bf16)v.z, (bf16)v.w };
    *(bf16x4*)(Xb + (size_t)i * 4) = o;
  }
  const float4* q4 = (const float4*)Wq;
  const float4* k4 = (const float4*)Wk;
  const float4* v4 = (const float4*)Wv;
  const float4* o4 = (const float4*)Wo;
  for (int i = tid; i < DMOD * DMOD / 4; i += nth) {
    float4 a = q4[i];
    float4 b = k4[i];
    float4 c = v4[i];
    float4 d = o4[i];
    *(bf16x4*)(Wqb + (size_t)i * 4) = bf16x4{ (bf16)a.x, (bf16)a.y, (bf16)a.z, (bf16)a.w };
    *(bf16x4*)(Wkb + (size_t)i * 4) = bf16x4{ (bf16)b.x, (bf16)b.y, (bf16)b.z, (bf16)b.w };
    *(bf16x4*)(Wvb + (size_t)i * 4) = bf16x4{ (bf16)c.x, (bf16)c.y, (bf16)c.z, (bf16)c.w };
    *(bf16x4*)(Wob + (size_t)i * 4) = bf16x4{ (bf16)d.x, (bf16)d.y, (bf16)d.z, (bf16)d.w };
  }
  for (int i = tid; i < SEQN * 32; i += nth) {
    const int s = i >> 5, p = i & 31;
    const float invf = (float)pow(10000.0, -(double)p / 32.0);
    const float ang = (float)s * invf;
    float sv, cv;
    sincosf(ang, &sv, &cv);
    ctab[i] = cv;
    stab[i] = sv;
  }
}

// ---------------------------------------------------------------- QKV gemm
// 128x128 tile, BK=32, 3-buffer LDS pipeline with counted vmcnt: tile s+2's
// global_load_lds stay in flight across the barriers; raw s_barrier.
__global__ __launch_bounds__(256) void gemm_qkv(
    const bf16* __restrict__ Xb,
    const bf16* __restrict__ Wqb, const bf16* __restrict__ Wkb, const bf16* __restrict__ Wvb,
    const float* __restrict__ bq, const float* __restrict__ bk, const float* __restrict__ bv,
    const float* __restrict__ ctab, const float* __restrict__ stab,
    bf16* __restrict__ Qb, bf16* __restrict__ Kb, bf16* __restrict__ Vtb)
{
  __shared__ bf16 sA[3][128 * 32];
  __shared__ bf16 sB[3][128 * 32];

  const int z = blockIdx.z;
  const bf16* Bm = (z == 0) ? Wqb : (z == 1) ? Wkb : Wvb;
  const float* bias = (z == 0) ? bq : (z == 1) ? bk : bv;

  const int t = threadIdx.x;
  const int lane = t & 63, l15 = lane & 15, g = lane >> 4;
  const int wave = t >> 6, wm = wave >> 1, wn = wave & 1;
  const int tileM = blockIdx.y * 128, tileN = blockIdx.x * 128;

  f32x4 acc[4][4] = {};

  const bf16* gA = Xb + (size_t)(tileM + (t >> 2)) * DMOD + (t & 3) * 8;
  const bf16* gB = Bm + (size_t)(tileN + (t >> 2)) * DMOD + (t & 3) * 8;

  auto stage = [&](int buf, int k0) {
    gload_lds16(gA + k0, &sA[buf][t * 8]);
    gload_lds16(gA + k0 + 64 * DMOD, &sA[buf][2048 + t * 8]);
    gload_lds16(gB + k0, &sB[buf][t * 8]);
    gload_lds16(gB + k0 + 64 * DMOD, &sB[buf][2048 + t * 8]);
  };

  stage(0, 0);
  stage(1, 32);

  const int NS = DMOD / 32;   // 32 K-steps
  int cur = 0;
  for (int s = 0; s < NS; ++s) {
    if (s + 2 < NS) {
      int pf = cur + 2; if (pf >= 3) pf -= 3;
      stage(pf, (s + 2) * 32);
      asm volatile("s_waitcnt vmcnt(8)" ::: "memory");   // tile s landed
    } else if (s + 1 < NS) {
      asm volatile("s_waitcnt vmcnt(4)" ::: "memory");
    } else {
      asm volatile("s_waitcnt vmcnt(0)" ::: "memory");
    }
    __builtin_amdgcn_s_barrier();
    asm volatile("" ::: "memory");

    const bf16* cA = sA[cur];
    const bf16* cB = sB[cur];
    bf16x8 af[4], bfr[4];
#pragma unroll
    for (int i = 0; i < 4; ++i)
      af[i] = *(const bf16x8*)(cA + (wm * 64 + i * 16 + l15) * 32 + g * 8);
#pragma unroll
    for (int j = 0; j < 4; ++j)
      bfr[j] = *(const bf16x8*)(cB + (wn * 64 + j * 16 + l15) * 32 + g * 8);
#pragma unroll
    for (int i = 0; i < 4; ++i)
#pragma unroll
      for (int j = 0; j < 4; ++j)
        acc[i][j] = __builtin_amdgcn_mfma_f32_16x16x32_bf16(af[i], bfr[j], acc[i][j], 0, 0, 0);

    asm volatile("" ::: "memory");
    __builtin_amdgcn_s_barrier();   // buf `cur` free for reuse
    cur = (cur == 2) ? 0 : cur + 1;
  }

#pragma unroll
  for (int j = 0; j < 4; ++j) {
    const int col = tileN + wn * 64 + j * 16 + l15;
    const float bcol = bias[col];
    const int h = col >> 6, d = col & 63;
#pragma unroll
    for (int i = 0; i < 4; ++i) {
#pragma unroll
      for (int r = 0; r < 4; ++r) {
        const int row = tileM + wm * 64 + i * 16 + g * 4 + r;
        const int b = row >> 11, s = row & (SEQN - 1);
        const float v = acc[i][j][r] + bcol;
        if (z != 2) {
          const int pair = d >> 1;
          const float cv = ctab[s * 32 + pair];
          const float sv = stab[s * 32 + pair];
          const float partner = __shfl_xor(v, 1);
          float rv = (d & 1) ? (partner * sv + v * cv) : (v * cv - partner * sv);
          if (z == 0) rv *= QSCALE_LOG2E;   // fold softmax scale+log2e into Q
          bf16* dst = (z == 0) ? Qb : Kb;
          dst[(((size_t)(b * NHEAD + h)) * SEQN + s) * DHEAD + d] = (bf16)rv;
        } else {
          Vtb[(((size_t)(b * NHEAD + h)) * DHEAD + d) * VSTR + s] = (bf16)v;
        }
      }
    }
  }
}

// ---------------------------------------------------------------- attention
// 1024 blocks (32 strip-pairs x 32 bh; bid&31=bh -> XCD-local heads), 4 waves.
// Each 32-row strip split across two waves (KV halves), KVBLK=32 tiles:
// per-iter live set (K[4]=16, V[2][2]=16, sc=16, qf=16 VGPRs + acc in AGPR)
// fits the register file -> no AGPR shuttling. In-place softmax on the MFMA
// result vector, defer-max (THR=8), per-lane l (combined once at end).
// K reloaded after QK^T, V after PV. End-of-kernel LDS merge per strip.
__global__ __launch_bounds__(256) void attn_kernel(
    const bf16* __restrict__ Qb, const bf16* __restrict__ Kb,
    const bf16* __restrict__ Vt, bf16* __restrict__ AO)
{
  __shared__ float sMrg[2][64][35];   // [strip_in_block][lane][a0(16),a1(16),m,l]

  const int t = threadIdx.x;
  const int lane = t & 63, l31 = lane & 31, hi = lane >> 5;
  const int wave = t >> 6;
  const int sb = wave >> 1;       // strip in block (0/1)
  const int half = wave & 1;      // 0: low KV half, 1: high KV half

  const int bid = blockIdx.x;
  const int bh = bid & 31;                 // bid%8 == bh%8
  const int grp = bid >> 8;                // 0..3 (round of 256)
  const int w = (bid >> 5) & 7;
  const int jq = (grp == 0) ? (31 - w) : (grp == 1) ? (16 + w)
               : (grp == 2) ? (15 - w) : w;
  const int qbase = (2 * jq + sb) * 32;
  const int qg = qbase + l31;              // this lane's q-row
  const int n32 = 2 * jq + sb + 1;         // 32-key KV tiles covering strip
  const int nA = (n32 + 1) >> 1;
  const int kv_lo = half ? nA : 0;
  const int kv_hi = half ? n32 : nA;

  const bf16* Kp = Kb + (size_t)bh * SEQN * DHEAD;
  const bf16* Vp = Vt + (size_t)bh * DHEAD * VSTR;
  const bf16* Qp = Qb + (size_t)bh * SEQN * DHEAD;
  const int b = bh >> 4, h = bh & 15;

  // K A-frag (32 keys): row=key=l31, k=8hi+e, d=16ch+8hi+e
  auto loadK = [&](bf16x8 (&K)[4], int kv0) {
#pragma unroll
    for (int ch = 0; ch < 4; ++ch)
      K[ch] = *(const bf16x8*)(Kp + (size_t)(kv0 + l31) * DHEAD + 16 * ch + 8 * hi);
  };
  // Vt A-frag: row=d=32*dblk+l31, k=8hi+e, key=kv0+16*kh+8hi+e
  auto loadV = [&](bf16x8 (&V)[2][2], int kv0) {
#pragma unroll
    for (int dblk = 0; dblk < 2; ++dblk)
#pragma unroll
      for (int kh = 0; kh < 2; ++kh)
        V[dblk][kh] = *(const bf16x8*)(Vp + (size_t)(dblk * 32 + l31) * VSTR + kv0 + 16 * kh + 8 * hi);
  };

  bf16x8 qf[4];   // Q B-frag: col=q=l31, k=8hi+e (d=16ch+8hi+e)
#pragma unroll
  for (int ch = 0; ch < 4; ++ch)
    qf[ch] = *(const bf16x8*)(Qp + (size_t)qg * DHEAD + 16 * ch + 8 * hi);

  f32x16 a0 = {}, a1 = {};
  float m = -1e30f, l = 0.f;   // l: per-lane over OWN 16 keys/tile

  if (kv_lo < kv_hi) {
    bf16x8 K[4];
    bf16x8 V[2][2];
    loadK(K, kv_lo * 32);
    loadV(V, kv_lo * 32);

    for (int it = kv_lo; it < kv_hi; ++it) {
      const int kv0 = it * 32;

      // ---- QK^T over 32 keys (consumes K); sc col=q=l31,
      //      row=key_local=(i&3)+8*(i>>2)+4hi
      f32x16 sc = {};
#pragma unroll
      for (int ch = 0; ch < 4; ++ch)
        sc = __builtin_amdgcn_mfma_f32_32x32x16_bf16(K[ch], qf[ch], sc, 0, 0, 0);
      if (it + 1 < kv_hi) loadK(K, kv0 + 32);   // hides under softmax+PV

      if (kv0 + 31 > qbase) {   // diagonal tile: causal mask (key > q)
#pragma unroll
        for (int i = 0; i < 16; ++i) {
          const int key = kv0 + (i & 3) + 8 * (i >> 2) + 4 * hi;
          if (key > qg) sc[i] = -1e30f;
        }
      }

      // own max tree (15 ops, in place)
      float red[8];
#pragma unroll
      for (int i = 0; i < 8; ++i) red[i] = fmaxf(sc[i], sc[i + 8]);
#pragma unroll
      for (int st = 4; st >= 1; st >>= 1)
#pragma unroll
        for (int i = 0; i < st; ++i) red[i] = fmaxf(red[i], red[i + st]);
      const float tmax_own = red[0];

      // defer-max: wave-uniform branch; in-branch shuffle syncs m across
      // partner halves
      if (__any(tmax_own > m + DEFER_THR)) {
        const float tfull = fmaxf(tmax_own, __shfl_xor(tmax_own, 32));
        const float mnew = fmaxf(m, tfull);
        const float alpha = __builtin_amdgcn_exp2f(m - mnew);
        m = mnew;
        l *= alpha;
#pragma unroll
        for (int i = 0; i < 16; ++i) { a0[i] *= alpha; a1[i] *= alpha; }
      }

      // p = exp2(s - m) in place; per-lane sum over own 16 keys
#pragma unroll
      for (int i = 0; i < 16; ++i) sc[i] = __builtin_amdgcn_exp2f(sc[i] - m);
#pragma unroll
      for (int i = 0; i < 8; ++i) red[i] = sc[i] + sc[i + 8];
#pragma unroll
      for (int st = 4; st >= 1; st >>= 1)
#pragma unroll
        for (int i = 0; i < st; ++i) red[i] += red[i + st];
      l += red[0];

      // P B-frags (K=16 each) + PV. For PV khalf kh, B reg r holds keys
      // 16kh+8hi+2r+b; holder of key k' is bit2(k'), at sc[(k'&3)+4*(k'>>3)].
      // own-needed base: sc[8kh+4hi..+3]; send base: sc[8kh+4-4hi..+3].
#pragma unroll
      for (int kh = 0; kh < 2; ++kh) {
        const uint32_t W0 = cvtpk(sc[8 * kh + 0], sc[8 * kh + 1]);
        const uint32_t W1 = cvtpk(sc[8 * kh + 2], sc[8 * kh + 3]);
        const uint32_t W2 = cvtpk(sc[8 * kh + 4], sc[8 * kh + 5]);
        const uint32_t W3 = cvtpk(sc[8 * kh + 6], sc[8 * kh + 7]);
        // hi=0 sends its upper half (W2,W3); hi=1 sends its lower (W0,W1)
        const uint32_t s0w = hi ? W0 : W2;
        const uint32_t s1w = hi ? W1 : W3;
        const uint32_t x0 = (uint32_t)__shfl_xor((int)s0w, 32);
        const uint32_t x1 = (uint32_t)__shfl_xor((int)s1w, 32);
        u32x4 pw;
        pw[0] = hi ? x0 : W0;   // keys 16kh+8hi+{0,1}
        pw[1] = hi ? x1 : W1;   // +{2,3}
        pw[2] = hi ? W2 : x0;   // +{4,5}
        pw[3] = hi ? W3 : x1;   // +{6,7}
        const bf16x8 pf = __builtin_bit_cast(bf16x8, pw);
        a0 = __builtin_amdgcn_mfma_f32_32x32x16_bf16(V[0][kh], pf, a0, 0, 0, 0);
        a1 = __builtin_amdgcn_mfma_f32_32x32x16_bf16(V[1][kh], pf, a1, 0, 0, 0);
      }
      if (it + 1 < kv_hi) loadV(V, kv0 + 32);   // hides under next QK^T
    }
  }

  // full-row l for this wave's kv range (one shuffle, once)
  const float l_full = l + __shfl_xor(l, 32);

  // ---- merge the two KV halves of each strip (half1 -> LDS, half0 merges)
  if (half) {
#pragma unroll
    for (int i = 0; i < 16; ++i) {
      sMrg[sb][lane][i] = a0[i];
      sMrg[sb][lane][16 + i] = a1[i];
    }
    sMrg[sb][lane][32] = m;
    sMrg[sb][lane][33] = l_full;
  }
  __syncthreads();
  if (!half) {
    const float mB = sMrg[sb][lane][32];
    const float lB = sMrg[sb][lane][33];
    const float ms = fmaxf(m, mB);
    const float fA = __builtin_amdgcn_exp2f(m - ms);
    const float fB = __builtin_amdgcn_exp2f(mB - ms);
    const float linv = 1.f / (l_full * fA + lB * fB);
    const size_t rowoff = ((size_t)(b * SEQN + qg)) * DMOD + h * DHEAD;
#pragma unroll
    for (int dblk = 0; dblk < 2; ++dblk) {
      const f32x16& av = dblk ? a1 : a0;
#pragma unroll
      for (int rg = 0; rg < 4; ++rg) {
        const int d0 = dblk * 32 + rg * 8 + 4 * hi;
        bf16x4 ov;
#pragma unroll
        for (int e = 0; e < 4; ++e)
          ov[e] = (bf16)((av[rg * 4 + e] * fA + sMrg[sb][lane][dblk * 16 + rg * 4 + e] * fB) * linv);
        *(bf16x4*)(AO + rowoff + d0) = ov;
      }
    }
  }
}

// ---------------------------------------------------------------- out gemm
__global__ __launch_bounds__(256) void gemm_out(
    const bf16* __restrict__ AO, const bf16* __restrict__ Wob,
    const float* __restrict__ bo, float* __restrict__ out)
{
  __shared__ bf16 sA[3][128 * 32];
  __shared__ bf16 sB[3][128 * 32];

  const int t = threadIdx.x;
  const int lane = t & 63, l15 = lane & 15, g = lane >> 4;
  const int wave = t >> 6, wm = wave >> 1, wn = wave & 1;
  const int tileM = blockIdx.y * 128, tileN = blockIdx.x * 128;

  f32x4 acc[4][4] = {};

  const bf16* gA = AO + (size_t)(tileM + (t >> 2)) * DMOD + (t & 3) * 8;
  const bf16* gB = Wob + (size_t)(tileN + (t >> 2)) * DMOD + (t & 3) * 8;

  auto stage = [&](int buf, int k0) {
    gload_lds16(gA + k0, &sA[buf][t * 8]);
    gload_lds16(gA + k0 + 64 * DMOD, &sA[buf][2048 + t * 8]);
    gload_lds16(gB + k0, &sB[buf][t * 8]);
    gload_lds16(gB + k0 + 64 * DMOD, &sB[buf][2048 + t * 8]);
  };

  stage(0, 0);
  stage(1, 32);

  const int NS = DMOD / 32;
  int cur = 0;
  for (int s = 0; s < NS; ++s) {
    if (s + 2 < NS) {
      int pf = cur + 2; if (pf >= 3) pf -= 3;
      stage(pf, (s + 2) * 32);
      asm volatile("s_waitcnt vmcnt(8)" ::: "memory");
    } else if (s + 1 < NS) {
      asm volatile("s_waitcnt vmcnt(4)" ::: "memory");
    } else {
      asm volatile("s_waitcnt vmcnt(0)" ::: "memory");
    }
    __builtin_amdgcn_s_barrier();
    asm volatile("" ::: "memory");

    const bf16* cA = sA[cur];
    const bf16* cB = sB[cur];
    bf16x8 af[4], bfr[4];
#pragma unroll
    for (int i = 0; i < 4; ++i)
      af[i] = *(const bf16x8*)(cA + (wm * 64 + i * 16 + l15) * 32 + g * 8);
#pragma unroll
    for (int j = 0; j < 4; ++j)
      bfr[j] = *(const bf16x8*)(cB + (wn * 64 + j * 16 + l15) * 32 + g * 8);
#pragma unroll
    for (int i = 0; i < 4; ++i)
#pragma unroll
      for (int j = 0; j < 4; ++j)
        acc[i][j] = __builtin_amdgcn_mfma_f32_16x16x32_bf16(af[i], bfr[j], acc[i][j], 0, 0, 0);

    asm volatile("" ::: "memory");
    __builtin_amdgcn_s_barrier();
    cur = (cur == 2) ? 0 : cur + 1;
  }

#pragma unroll
  for (int j = 0; j < 4; ++j) {
    const int col = tileN + wn * 64 + j * 16 + l15;
    const float bcol = bo[col];
#pragma unroll
    for (int i = 0; i < 4; ++i)
#pragma unroll
      for (int r = 0; r < 4; ++r) {
        const int row = tileM + wm * 64 + i * 16 + g * 4 + r;
        out[(size_t)row * DMOD + col] = acc[i][j][r] + bcol;
      }
  }
}

// ---------------------------------------------------------------- launch
extern "C" void kernel_launch(void* const* d_in, const int* in_sizes, int n_in,
                              void* d_out, int out_size, void* d_ws, size_t ws_size,
                              hipStream_t stream)
{
  (void)in_sizes; (void)n_in; (void)out_size; (void)ws_size;
  const float* X  = (const float*)d_in[0];
  const float* Wq = (const float*)d_in[1];
  const float* bq = (const float*)d_in[2];
  const float* Wk = (const float*)d_in[3];
  const float* bk = (const float*)d_in[4];
  const float* Wv = (const float*)d_in[5];
  const float* bv = (const float*)d_in[6];
  const float* Wo = (const float*)d_in[7];
  const float* bo = (const float*)d_in[8];

  char* ws = (char*)d_ws;
  float* ctab = (float*)(ws + 0);
  float* stab = (float*)(ws + 262144);
  bf16* Xb  = (bf16*)(ws + 524288);
  bf16* Wqb = (bf16*)(ws + 8912896);
  bf16* Wkb = (bf16*)(ws + 11010048);
  bf16* Wvb = (bf16*)(ws + 13107200);
  bf16* Wob = (bf16*)(ws + 15204352);
  bf16* Qb  = (bf16*)(ws + 17301504);
  bf16* Kb  = (bf16*)(ws + 25690112);
  bf16* Vtb = (bf16*)(ws + 34078720);   // 32*64*2080*2 = 8519680 bytes
  bf16* AO  = (bf16*)(ws + 42598400);

  prep_kernel<<<1024, 256, 0, stream>>>(X, Wq, Wk, Wv, Wo, Xb, Wqb, Wkb, Wvb, Wob, ctab, stab);
  gemm_qkv<<<dim3(8, 32, 3), 256, 0, stream>>>(Xb, Wqb, Wkb, Wvb, bq, bk, bv, ctab, stab, Qb, Kb, Vtb);
  attn_kernel<<<1024, 256, 0, stream>>>(Qb, Kb, Vtb, AO);
  gemm_out<<<dim3(8, 32), 256, 0, stream>>>(AO, Wob, bo, (float*)d_out);
}

// Round 15
// 140.694 us; speedup vs baseline: 1.0456x; 1.0237x over previous
//
#include <hip/hip_runtime.h>
#include <hip/hip_bf16.h>
#include <stdint.h>
#include <math.h>

// CausalMultiheadRoPEAttn: B=2, S=2048, D=1024, H=16, Dh=64
// prep (bf16 casts + rope table) -> fused QKV gemm (+bias+rope; counted-vmcnt
// pipelined K-loop; NEW: LDS-staged coalesced epilogue stores, incl. the Vt
// transpose) -> flash attention (swapped-operand 32x32x16, KVBLK=32,
// in-register softmax, defer-max) -> out gemm (pipelined K-loop).

typedef __bf16 bf16;
typedef __attribute__((ext_vector_type(4))) __bf16 bf16x4;
typedef __attribute__((ext_vector_type(8))) __bf16 bf16x8;
typedef __attribute__((ext_vector_type(4))) float f32x4;
typedef __attribute__((ext_vector_type(16))) float f32x16;
typedef __attribute__((ext_vector_type(4))) uint32_t u32x4;

#define SEQN 2048
#define DMOD 1024
#define NHEAD 16
#define DHEAD 64
#define MTOT 4096
#define VSTR 2080   // padded Vt row stride (elements)
// 0.125 * log2(e): scores land in log2 domain -> softmax uses exp2
#define QSCALE_LOG2E 0.18033688011112042f
#define DEFER_THR 8.0f
#define EST 136     // epilogue staging stride (272B rows: 16B-aligned)

__device__ __forceinline__ void gload_lds16(const bf16* g, bf16* l) {
  __builtin_amdgcn_global_load_lds(
      (const __attribute__((address_space(1))) uint32_t*)g,
      (__attribute__((address_space(3))) uint32_t*)l,
      16, 0, 0);
}

__device__ __forceinline__ uint32_t cvtpk(float lo, float hi) {
  uint32_t r;
  asm("v_cvt_pk_bf16_f32 %0, %1, %2" : "=v"(r) : "v"(lo), "v"(hi));
  return r;
}

// ---------------------------------------------------------------- prep
__global__ __launch_bounds__(256) void prep_kernel(
    const float* __restrict__ X,
    const float* __restrict__ Wq, const float* __restrict__ Wk,
    const float* __restrict__ Wv, const float* __restrict__ Wo,
    bf16* __restrict__ Xb, bf16* __restrict__ Wqb, bf16* __restrict__ Wkb,
    bf16* __restrict__ Wvb, bf16* __restrict__ Wob,
    float* __restrict__ ctab, float* __restrict__ stab)
{
  const int tid = blockIdx.x * blockDim.x + threadIdx.x;
  const int nth = gridDim.x * blockDim.x;

  const float4* X4 = (const float4*)X;
  for (int i = tid; i < MTOT * DMOD / 4; i += nth) {
    float4 v = X4[i];
    bf16x4 o = { (bf16)v.x, (bf16)v.y, (bf16)v.z, (bf16)v.w };
    *(bf16x4*)(Xb + (size_t)i * 4) = o;
  }
  const float4* q4 = (const float4*)Wq;
  const float4* k4 = (const float4*)Wk;
  const float4* v4 = (const float4*)Wv;
  const float4* o4 = (const float4*)Wo;
  for (int i = tid; i < DMOD * DMOD / 4; i += nth) {
    float4 a = q4[i];
    float4 b = k4[i];
    float4 c = v4[i];
    float4 d = o4[i];
    *(bf16x4*)(Wqb + (size_t)i * 4) = bf16x4{ (bf16)a.x, (bf16)a.y, (bf16)a.z, (bf16)a.w };
    *(bf16x4*)(Wkb + (size_t)i * 4) = bf16x4{ (bf16)b.x, (bf16)b.y, (bf16)b.z, (bf16)b.w };
    *(bf16x4*)(Wvb + (size_t)i * 4) = bf16x4{ (bf16)c.x, (bf16)c.y, (bf16)c.z, (bf16)c.w };
    *(bf16x4*)(Wob + (size_t)i * 4) = bf16x4{ (bf16)d.x, (bf16)d.y, (bf16)d.z, (bf16)d.w };
  }
  for (int i = tid; i < SEQN * 32; i += nth) {
    const int s = i >> 5, p = i & 31;
    const float invf = (float)pow(10000.0, -(double)p / 32.0);
    const float ang = (float)s * invf;
    float sv, cv;
    sincosf(ang, &sv, &cv);
    ctab[i] = cv;
    stab[i] = sv;
  }
}

// ---------------------------------------------------------------- QKV gemm
// 128x128 tile, BK=32, 3-buffer LDS pipeline with counted vmcnt (unchanged).
// Epilogue: rope/bias in regs -> LDS stage ([s][d] for Q/K, [d][s] for Vt)
// -> coalesced 128B-run global stores (no more 2B scatters).
__global__ __launch_bounds__(256) void gemm_qkv(
    const bf16* __restrict__ Xb,
    const bf16* __restrict__ Wqb, const bf16* __restrict__ Wkb, const bf16* __restrict__ Wvb,
    const float* __restrict__ bq, const float* __restrict__ bk, const float* __restrict__ bv,
    const float* __restrict__ ctab, const float* __restrict__ stab,
    bf16* __restrict__ Qb, bf16* __restrict__ Kb, bf16* __restrict__ Vtb)
{
  __shared__ __align__(16) char smem[49152];   // 3x(A+B) staging / epi union
  bf16* const sAb = (bf16*)smem;               // [3][128*32]
  bf16* const sBb = (bf16*)smem + 12288;       // [3][128*32]
  bf16* const epi = (bf16*)smem;               // [128][EST] (34816 B)

  const int z = blockIdx.z;
  const bf16* Bm = (z == 0) ? Wqb : (z == 1) ? Wkb : Wvb;
  const float* bias = (z == 0) ? bq : (z == 1) ? bk : bv;

  const int t = threadIdx.x;
  const int lane = t & 63, l15 = lane & 15, g = lane >> 4;
  const int wave = t >> 6, wm = wave >> 1, wn = wave & 1;
  const int tileM = blockIdx.y * 128, tileN = blockIdx.x * 128;

  f32x4 acc[4][4] = {};

  const bf16* gA = Xb + (size_t)(tileM + (t >> 2)) * DMOD + (t & 3) * 8;
  const bf16* gB = Bm + (size_t)(tileN + (t >> 2)) * DMOD + (t & 3) * 8;

  auto stage = [&](int buf, int k0) {
    gload_lds16(gA + k0, sAb + buf * 4096 + t * 8);
    gload_lds16(gA + k0 + 64 * DMOD, sAb + buf * 4096 + 2048 + t * 8);
    gload_lds16(gB + k0, sBb + buf * 4096 + t * 8);
    gload_lds16(gB + k0 + 64 * DMOD, sBb + buf * 4096 + 2048 + t * 8);
  };

  stage(0, 0);
  stage(1, 32);

  const int NS = DMOD / 32;   // 32 K-steps
  int cur = 0;
  for (int s = 0; s < NS; ++s) {
    if (s + 2 < NS) {
      int pf = cur + 2; if (pf >= 3) pf -= 3;
      stage(pf, (s + 2) * 32);
      asm volatile("s_waitcnt vmcnt(8)" ::: "memory");   // tile s landed
    } else if (s + 1 < NS) {
      asm volatile("s_waitcnt vmcnt(4)" ::: "memory");
    } else {
      asm volatile("s_waitcnt vmcnt(0)" ::: "memory");
    }
    __builtin_amdgcn_s_barrier();
    asm volatile("" ::: "memory");

    const bf16* cA = sAb + cur * 4096;
    const bf16* cB = sBb + cur * 4096;
    bf16x8 af[4], bfr[4];
#pragma unroll
    for (int i = 0; i < 4; ++i)
      af[i] = *(const bf16x8*)(cA + (wm * 64 + i * 16 + l15) * 32 + g * 8);
#pragma unroll
    for (int j = 0; j < 4; ++j)
      bfr[j] = *(const bf16x8*)(cB + (wn * 64 + j * 16 + l15) * 32 + g * 8);
#pragma unroll
    for (int i = 0; i < 4; ++i)
#pragma unroll
      for (int j = 0; j < 4; ++j)
        acc[i][j] = __builtin_amdgcn_mfma_f32_16x16x32_bf16(af[i], bfr[j], acc[i][j], 0, 0, 0);

    asm volatile("" ::: "memory");
    __builtin_amdgcn_s_barrier();   // buf `cur` free for reuse
    cur = (cur == 2) ? 0 : cur + 1;
  }

  // ---- epilogue: regs -> LDS stage -> coalesced stores
  __syncthreads();   // all staging-buffer reads retired; LDS reusable

#pragma unroll
  for (int j = 0; j < 4; ++j) {
    const int colL = wn * 64 + j * 16 + l15;
    const int col = tileN + colL;
    const float bcol = bias[col];
    const int d = col & 63;
#pragma unroll
    for (int i = 0; i < 4; ++i) {
#pragma unroll
      for (int r = 0; r < 4; ++r) {
        const int rowL = wm * 64 + i * 16 + g * 4 + r;
        const int row = tileM + rowL;
        const int s = row & (SEQN - 1);
        const float v = acc[i][j][r] + bcol;
        if (z != 2) {
          const int pair = d >> 1;
          const float cv = ctab[s * 32 + pair];
          const float sv = stab[s * 32 + pair];
          const float partner = __shfl_xor(v, 1);
          float rv = (d & 1) ? (partner * sv + v * cv) : (v * cv - partner * sv);
          if (z == 0) rv *= QSCALE_LOG2E;
          epi[rowL * EST + colL] = (bf16)rv;     // [s][d]
        } else {
          epi[colL * EST + rowL] = (bf16)v;      // [d][s] (transpose for Vt)
        }
      }
    }
  }
  __syncthreads();

  // readback: 256 threads x (one 128-row, one 64-col half) = 128B runs
  const int rrow = t >> 1, rh = t & 1;
  const bf16* src = epi + rrow * EST + rh * 64;
  if (z != 2) {
    const int row_g = tileM + rrow;
    const int b = row_g >> 11, s = row_g & (SEQN - 1);
    const int h = (tileN + rh * 64) >> 6;
    bf16* dst = ((z == 0) ? Qb : Kb) + (((size_t)(b * NHEAD + h)) * SEQN + s) * DHEAD;
#pragma unroll
    for (int k = 0; k < 8; ++k)
      *(bf16x8*)(dst + k * 8) = *(const bf16x8*)(src + k * 8);
  } else {
    const int col_g = tileN + rrow;
    const int h = col_g >> 6, dd = col_g & 63;
    const int b = tileM >> 11;
    const int sbase = (tileM & (SEQN - 1)) + rh * 64;
    bf16* dst = Vtb + (((size_t)(b * NHEAD + h)) * DHEAD + dd) * VSTR + sbase;
#pragma unroll
    for (int k = 0; k < 8; ++k)
      *(bf16x8*)(dst + k * 8) = *(const bf16x8*)(src + k * 8);
  }
}

// ---------------------------------------------------------------- attention
// (unchanged from R14 passing build)
__global__ __launch_bounds__(256) void attn_kernel(
    const bf16* __restrict__ Qb, const bf16* __restrict__ Kb,
    const bf16* __restrict__ Vt, bf16* __restrict__ AO)
{
  __shared__ float sMrg[2][64][35];

  const int t = threadIdx.x;
  const int lane = t & 63, l31 = lane & 31, hi = lane >> 5;
  const int wave = t >> 6;
  const int sb = wave >> 1;
  const int half = wave & 1;

  const int bid = blockIdx.x;
  const int bh = bid & 31;
  const int grp = bid >> 8;
  const int w = (bid >> 5) & 7;
  const int jq = (grp == 0) ? (31 - w) : (grp == 1) ? (16 + w)
               : (grp == 2) ? (15 - w) : w;
  const int qbase = (2 * jq + sb) * 32;
  const int qg = qbase + l31;
  const int n32 = 2 * jq + sb + 1;
  const int nA = (n32 + 1) >> 1;
  const int kv_lo = half ? nA : 0;
  const int kv_hi = half ? n32 : nA;

  const bf16* Kp = Kb + (size_t)bh * SEQN * DHEAD;
  const bf16* Vp = Vt + (size_t)bh * DHEAD * VSTR;
  const bf16* Qp = Qb + (size_t)bh * SEQN * DHEAD;
  const int b = bh >> 4, h = bh & 15;

  auto loadK = [&](bf16x8 (&K)[4], int kv0) {
#pragma unroll
    for (int ch = 0; ch < 4; ++ch)
      K[ch] = *(const bf16x8*)(Kp + (size_t)(kv0 + l31) * DHEAD + 16 * ch + 8 * hi);
  };
  auto loadV = [&](bf16x8 (&V)[2][2], int kv0) {
#pragma unroll
    for (int dblk = 0; dblk < 2; ++dblk)
#pragma unroll
      for (int kh = 0; kh < 2; ++kh)
        V[dblk][kh] = *(const bf16x8*)(Vp + (size_t)(dblk * 32 + l31) * VSTR + kv0 + 16 * kh + 8 * hi);
  };

  bf16x8 qf[4];
#pragma unroll
  for (int ch = 0; ch < 4; ++ch)
    qf[ch] = *(const bf16x8*)(Qp + (size_t)qg * DHEAD + 16 * ch + 8 * hi);

  f32x16 a0 = {}, a1 = {};
  float m = -1e30f, l = 0.f;

  if (kv_lo < kv_hi) {
    bf16x8 K[4];
    bf16x8 V[2][2];
    loadK(K, kv_lo * 32);
    loadV(V, kv_lo * 32);

    for (int it = kv_lo; it < kv_hi; ++it) {
      const int kv0 = it * 32;

      f32x16 sc = {};
#pragma unroll
      for (int ch = 0; ch < 4; ++ch)
        sc = __builtin_amdgcn_mfma_f32_32x32x16_bf16(K[ch], qf[ch], sc, 0, 0, 0);
      if (it + 1 < kv_hi) loadK(K, kv0 + 32);

      if (kv0 + 31 > qbase) {
#pragma unroll
        for (int i = 0; i < 16; ++i) {
          const int key = kv0 + (i & 3) + 8 * (i >> 2) + 4 * hi;
          if (key > qg) sc[i] = -1e30f;
        }
      }

      float red[8];
#pragma unroll
      for (int i = 0; i < 8; ++i) red[i] = fmaxf(sc[i], sc[i + 8]);
#pragma unroll
      for (int st = 4; st >= 1; st >>= 1)
#pragma unroll
        for (int i = 0; i < st; ++i) red[i] = fmaxf(red[i], red[i + st]);
      const float tmax_own = red[0];

      if (__any(tmax_own > m + DEFER_THR)) {
        const float tfull = fmaxf(tmax_own, __shfl_xor(tmax_own, 32));
        const float mnew = fmaxf(m, tfull);
        const float alpha = __builtin_amdgcn_exp2f(m - mnew);
        m = mnew;
        l *= alpha;
#pragma unroll
        for (int i = 0; i < 16; ++i) { a0[i] *= alpha; a1[i] *= alpha; }
      }

#pragma unroll
      for (int i = 0; i < 16; ++i) sc[i] = __builtin_amdgcn_exp2f(sc[i] - m);
#pragma unroll
      for (int i = 0; i < 8; ++i) red[i] = sc[i] + sc[i + 8];
#pragma unroll
      for (int st = 4; st >= 1; st >>= 1)
#pragma unroll
        for (int i = 0; i < st; ++i) red[i] += red[i + st];
      l += red[0];

#pragma unroll
      for (int kh = 0; kh < 2; ++kh) {
        const uint32_t W0 = cvtpk(sc[8 * kh + 0], sc[8 * kh + 1]);
        const uint32_t W1 = cvtpk(sc[8 * kh + 2], sc[8 * kh + 3]);
        const uint32_t W2 = cvtpk(sc[8 * kh + 4], sc[8 * kh + 5]);
        const uint32_t W3 = cvtpk(sc[8 * kh + 6], sc[8 * kh + 7]);
        const uint32_t s0w = hi ? W0 : W2;
        const uint32_t s1w = hi ? W1 : W3;
        const uint32_t x0 = (uint32_t)__shfl_xor((int)s0w, 32);
        const uint32_t x1 = (uint32_t)__shfl_xor((int)s1w, 32);
        u32x4 pw;
        pw[0] = hi ? x0 : W0;
        pw[1] = hi ? x1 : W1;
        pw[2] = hi ? W2 : x0;
        pw[3] = hi ? W3 : x1;
        const bf16x8 pf = __builtin_bit_cast(bf16x8, pw);
        a0 = __builtin_amdgcn_mfma_f32_32x32x16_bf16(V[0][kh], pf, a0, 0, 0, 0);
        a1 = __builtin_amdgcn_mfma_f32_32x32x16_bf16(V[1][kh], pf, a1, 0, 0, 0);
      }
      if (it + 1 < kv_hi) loadV(V, kv0 + 32);
    }
  }

  const float l_full = l + __shfl_xor(l, 32);

  if (half) {
#pragma unroll
    for (int i = 0; i < 16; ++i) {
      sMrg[sb][lane][i] = a0[i];
      sMrg[sb][lane][16 + i] = a1[i];
    }
    sMrg[sb][lane][32] = m;
    sMrg[sb][lane][33] = l_full;
  }
  __syncthreads();
  if (!half) {
    const float mB = sMrg[sb][lane][32];
    const float lB = sMrg[sb][lane][33];
    const float ms = fmaxf(m, mB);
    const float fA = __builtin_amdgcn_exp2f(m - ms);
    const float fB = __builtin_amdgcn_exp2f(mB - ms);
    const float linv = 1.f / (l_full * fA + lB * fB);
    const size_t rowoff = ((size_t)(b * SEQN + qg)) * DMOD + h * DHEAD;
#pragma unroll
    for (int dblk = 0; dblk < 2; ++dblk) {
      const f32x16& av = dblk ? a1 : a0;
#pragma unroll
      for (int rg = 0; rg < 4; ++rg) {
        const int d0 = dblk * 32 + rg * 8 + 4 * hi;
        bf16x4 ov;
#pragma unroll
        for (int e = 0; e < 4; ++e)
          ov[e] = (bf16)((av[rg * 4 + e] * fA + sMrg[sb][lane][dblk * 16 + rg * 4 + e] * fB) * linv);
        *(bf16x4*)(AO + rowoff + d0) = ov;
      }
    }
  }
}

// ---------------------------------------------------------------- out gemm
__global__ __launch_bounds__(256) void gemm_out(
    const bf16* __restrict__ AO, const bf16* __restrict__ Wob,
    const float* __restrict__ bo, float* __restrict__ out)
{
  __shared__ bf16 sA[3][128 * 32];
  __shared__ bf16 sB[3][128 * 32];

  const int t = threadIdx.x;
  const int lane = t & 63, l15 = lane & 15, g = lane >> 4;
  const int wave = t >> 6, wm = wave >> 1, wn = wave & 1;
  const int tileM = blockIdx.y * 128, tileN = blockIdx.x * 128;

  f32x4 acc[4][4] = {};

  const bf16* gA = AO + (size_t)(tileM + (t >> 2)) * DMOD + (t & 3) * 8;
  const bf16* gB = Wob + (size_t)(tileN + (t >> 2)) * DMOD + (t & 3) * 8;

  auto stage = [&](int buf, int k0) {
    gload_lds16(gA + k0, &sA[buf][t * 8]);
    gload_lds16(gA + k0 + 64 * DMOD, &sA[buf][2048 + t * 8]);
    gload_lds16(gB + k0, &sB[buf][t * 8]);
    gload_lds16(gB + k0 + 64 * DMOD, &sB[buf][2048 + t * 8]);
  };

  stage(0, 0);
  stage(1, 32);

  const int NS = DMOD / 32;
  int cur = 0;
  for (int s = 0; s < NS; ++s) {
    if (s + 2 < NS) {
      int pf = cur + 2; if (pf >= 3) pf -= 3;
      stage(pf, (s + 2) * 32);
      asm volatile("s_waitcnt vmcnt(8)" ::: "memory");
    } else if (s + 1 < NS) {
      asm volatile("s_waitcnt vmcnt(4)" ::: "memory");
    } else {
      asm volatile("s_waitcnt vmcnt(0)" ::: "memory");
    }
    __builtin_amdgcn_s_barrier();
    asm volatile("" ::: "memory");

    const bf16* cA = sA[cur];
    const bf16* cB = sB[cur];
    bf16x8 af[4], bfr[4];
#pragma unroll
    for (int i = 0; i < 4; ++i)
      af[i] = *(const bf16x8*)(cA + (wm * 64 + i * 16 + l15) * 32 + g * 8);
#pragma unroll
    for (int j = 0; j < 4; ++j)
      bfr[j] = *(const bf16x8*)(cB + (wn * 64 + j * 16 + l15) * 32 + g * 8);
#pragma unroll
    for (int i = 0; i < 4; ++i)
#pragma unroll
      for (int j = 0; j < 4; ++j)
        acc[i][j] = __builtin_amdgcn_mfma_f32_16x16x32_bf16(af[i], bfr[j], acc[i][j], 0, 0, 0);

    asm volatile("" ::: "memory");
    __builtin_amdgcn_s_barrier();
    cur = (cur == 2) ? 0 : cur + 1;
  }

#pragma unroll
  for (int j = 0; j < 4; ++j) {
    const int col = tileN + wn * 64 + j * 16 + l15;
    const float bcol = bo[col];
#pragma unroll
    for (int i = 0; i < 4; ++i)
#pragma unroll
      for (int r = 0; r < 4; ++r) {
        const int row = tileM + wm * 64 + i * 16 + g * 4 + r;
        out[(size_t)row * DMOD + col] = acc[i][j][r] + bcol;
      }
  }
}

// ---------------------------------------------------------------- launch
extern "C" void kernel_launch(void* const* d_in, const int* in_sizes, int n_in,
                              void* d_out, int out_size, void* d_ws, size_t ws_size,
                              hipStream_t stream)
{
  (void)in_sizes; (void)n_in; (void)out_size; (void)ws_size;
  const float* X  = (const float*)d_in[0];
  const float* Wq = (const float*)d_in[1];
  const float* bq = (const float*)d_in[2];
  const float* Wk = (const float*)d_in[3];
  const float* bk = (const float*)d_in[4];
  const float* Wv = (const float*)d_in[5];
  const float* bv = (const float*)d_in[6];
  const float* Wo = (const float*)d_in[7];
  const float* bo = (const float*)d_in[8];

  char* ws = (char*)d_ws;
  float* ctab = (float*)(ws + 0);
  float* stab = (float*)(ws + 262144);
  bf16* Xb  = (bf16*)(ws + 524288);
  bf16* Wqb = (bf16*)(ws + 8912896);
  bf16* Wkb = (bf16*)(ws + 11010048);
  bf16* Wvb = (bf16*)(ws + 13107200);
  bf16* Wob = (bf16*)(ws + 15204352);
  bf16* Qb  = (bf16*)(ws + 17301504);
  bf16* Kb  = (bf16*)(ws + 25690112);
  bf16* Vtb = (bf16*)(ws + 34078720);   // 32*64*2080*2 = 8519680 bytes
  bf16* AO  = (bf16*)(ws + 42598400);

  prep_kernel<<<1024, 256, 0, stream>>>(X, Wq, Wk, Wv, Wo, Xb, Wqb, Wkb, Wvb, Wob, ctab, stab);
  gemm_qkv<<<dim3(8, 32, 3), 256, 0, stream>>>(Xb, Wqb, Wkb, Wvb, bq, bk, bv, ctab, stab, Qb, Kb, Vtb);
  attn_kernel<<<1024, 256, 0, stream>>>(Qb, Kb, Vtb, AO);
  gemm_out<<<dim3(8, 32), 256, 0, stream>>>(AO, Wob, bo, (float*)d_out);
}